// Round 9
// baseline (918.697 us; speedup 1.0000x reference)
//
#include <hip/hip_runtime.h>
#include <hip/hip_bf16.h>

using bf16_t = __hip_bfloat16;
typedef __attribute__((ext_vector_type(8))) __bf16 bfrag;   // 8 bf16 = 4 VGPR (MFMA A/B operand)
typedef __attribute__((ext_vector_type(4))) float f32x4;    // MFMA C/D operand

#define MFMA16(a, b, c) __builtin_amdgcn_mfma_f32_16x16x32_bf16((a), (b), (c), 0, 0, 0)

__device__ __forceinline__ void gload_lds16(const void* g, void* l) {
  // async global->LDS, 16B/lane; LDS dest = wave-uniform base + lane*16
  __builtin_amdgcn_global_load_lds((const __attribute__((address_space(1))) void*)g,
                                   (__attribute__((address_space(3))) void*)l, 16, 0, 0);
}

__device__ __forceinline__ float bf2f(unsigned u) { return __uint_as_float(u << 16); }

// ---------- weight transpose + f32->bf16 convert: in[K][N] f32 -> out[N][K] bf16 ----------
__global__ __launch_bounds__(256) void transpose_cvt(const float* __restrict__ in,
    bf16_t* __restrict__ out, int K, int N) {
  __shared__ float t[64][65];
  const int n0 = blockIdx.x * 64, k0 = blockIdx.y * 64;
  const int tx = threadIdx.x & 15, ty = threadIdx.x >> 4;   // 16 x 16
#pragma unroll
  for (int i = 0; i < 4; ++i) {
    float4 v = *(const float4*)&in[(size_t)(k0 + i * 16 + ty) * N + n0 + tx * 4];
    t[i * 16 + ty][tx * 4 + 0] = v.x; t[i * 16 + ty][tx * 4 + 1] = v.y;
    t[i * 16 + ty][tx * 4 + 2] = v.z; t[i * 16 + ty][tx * 4 + 3] = v.w;
  }
  __syncthreads();
#pragma unroll
  for (int i = 0; i < 4; ++i) {
    const int n = i * 16 + ty;
    bf16_t w[4];
#pragma unroll
    for (int j = 0; j < 4; ++j) w[j] = bf16_t(t[tx * 4 + j][n]);
    *(uint2*)&out[(size_t)(n0 + n) * K + k0 + tx * 4] = *(const uint2*)w;
  }
}

// ---------- LayerNorm: x f32 [2048][2048] -> h bf16 ----------
__global__ __launch_bounds__(256) void ln_kernel(const float* __restrict__ x,
    const float* __restrict__ sc, const float* __restrict__ of, bf16_t* __restrict__ h) {
  __shared__ float red[8];
  const int n = blockIdx.x, tid = threadIdx.x;
  const float* xr = x + (size_t)n * 2048;
  float4 a = ((const float4*)xr)[tid * 2];
  float4 b = ((const float4*)xr)[tid * 2 + 1];
  float s = a.x + a.y + a.z + a.w + b.x + b.y + b.z + b.w;
  float q = a.x * a.x + a.y * a.y + a.z * a.z + a.w * a.w +
            b.x * b.x + b.y * b.y + b.z * b.z + b.w * b.w;
#pragma unroll
  for (int m = 32; m; m >>= 1) { s += __shfl_xor(s, m); q += __shfl_xor(q, m); }
  if ((tid & 63) == 0) { red[(tid >> 6) * 2] = s; red[(tid >> 6) * 2 + 1] = q; }
  __syncthreads();
  s = red[0] + red[2] + red[4] + red[6];
  q = red[1] + red[3] + red[5] + red[7];
  const float mu = s * (1.f / 2048.f);
  const float inv = rsqrtf(q * (1.f / 2048.f) - mu * mu + 1e-5f);
  const int base = tid * 8;
  float v[8] = {a.x, a.y, a.z, a.w, b.x, b.y, b.z, b.w};
  bf16_t* hr = h + (size_t)n * 2048 + base;
#pragma unroll
  for (int j = 0; j < 8; ++j) hr[j] = bf16_t((v[j] - mu) * inv * sc[base + j] + of[base + j]);
}

// ---------- 8-phase cross-prefetch 256x256 GEMM: C = A[M][lda](bf16) * BT[N][ldb]^T ----------
// Gray-code quadrants per K-tile: Q_A(aL,b01) Q_D(aL,b23) Q_C(aH,b23) Q_B(aH,b01).
// Each phase ISSUES the next phase's ds_reads, then barrier + COUNTED lgkmcnt (drains
// only prior-phase reads) so MFMA overlaps the LDS service of the next phase's reads.
// Stages: Ph3 SA(t+2), Ph4 SB(t+2); vmcnt(4) before Ph3-barrier confirms tile t+1.
// EPI bits: 1=+bias, 2=gelu, 8=store bf16 (else f32)
template <int EPI>
__global__ __launch_bounds__(512, 2) void gemm8p(
    const bf16_t* __restrict__ A, int lda, const bf16_t* __restrict__ BT, int ldb,
    const float* __restrict__ bias, float* __restrict__ Cf, bf16_t* __restrict__ Cb,
    int M, int N, int K, size_t splitStride) {
  extern __shared__ __align__(16) char lds[];   // 128 KiB
  const int tid = threadIdx.x, wid = tid >> 6, lane = tid & 63;
  const int lc = lane & 15, lg = lane >> 4;
  const int bm = blockIdx.y * 256, bn = blockIdx.x * 256;
  const int wr = wid >> 2, wc = wid & 3;              // 2M x 4N waves, each 128x64 out
  const int NT = K >> 6;                              // K-tiles of 64 (NT even, >=8)
  // staging geometry: lds off = slot + tid*16 (+8192 for j=1) -> row=tid>>3, chunk pos=tid&7
  // swizzle: pos p holds global chunk p ^ (row&7)
  const int srow = tid >> 3;
  const int scol = (((tid & 7) ^ ((tid >> 3) & 7)) << 3);
  const bf16_t* Abase = A + (size_t)blockIdx.z * K + (size_t)(bm + srow) * lda + scol;
  const bf16_t* Bbase = BT + (size_t)blockIdx.z * K + (size_t)(bn + srow) * ldb + scol;
  auto SA = [&](int T, int h) {
    char* dst = lds + (T & 1) * 32768 + h * 16384 + wid * 1024;
    const bf16_t* src = Abase + (size_t)(h * 128) * lda + T * 64;
    gload_lds16(src, dst); gload_lds16(src + (size_t)64 * lda, dst + 8192);
  };
  auto SB = [&](int T, int h) {
    char* dst = lds + 65536 + (T & 1) * 32768 + h * 16384 + wid * 1024;
    const bf16_t* src = Bbase + (size_t)(h * 128) * ldb + T * 64;
    gload_lds16(src, dst); gload_lds16(src + (size_t)64 * ldb, dst + 8192);
  };
#define FRA(D, row, kk) (*(const bfrag*)(lds + (D) * 32768 + wr * 16384 + (row) * 128 + \
    ((((kk) * 4 + lg) ^ ((row) & 7)) << 4)))
#define FRB(D, row, kk) (*(const bfrag*)(lds + 65536 + (D) * 32768 + (wc >> 1) * 16384 + \
    (row) * 128 + ((((kk) * 4 + lg) ^ ((row) & 7)) << 4)))

  // prologue: tiles 0 and 1 fully staged (16 gloads)
  SA(0, 0); SA(0, 1); SB(0, 0); SB(0, 1);
  SA(1, 0); SA(1, 1); SB(1, 0); SB(1, 1);
  asm volatile("s_waitcnt vmcnt(8)" ::: "memory");    // tile0 landed
  __builtin_amdgcn_s_barrier();

  f32x4 acc[8][4] = {};
  bfrag aL[4][2], aH[4][2], b01A[2][2], b01B[2][2], b23v[2][2];
  const int brl = (wc & 1) * 64 + lc;                 // B local row base (+n*16)
#pragma unroll
  for (int m = 0; m < 4; ++m)
#pragma unroll
    for (int kk = 0; kk < 2; ++kk) aL[m][kk] = FRA(0, m * 16 + lc, kk);
#pragma unroll
  for (int n = 0; n < 2; ++n)
#pragma unroll
    for (int kk = 0; kk < 2; ++kk) b01A[n][kk] = FRB(0, brl + n * 16, kk);

  auto tile_body = [&](int T, int D, bfrag (&B01C)[2][2], bfrag (&B01N)[2][2]) {
    // ---- Ph1: issue b23(D) [4]; MFMA Q_A = acc[m0-3][n01] (aL x B01C)
#pragma unroll
    for (int n = 0; n < 2; ++n)
#pragma unroll
      for (int kk = 0; kk < 2; ++kk) b23v[n][kk] = FRB(D, brl + (n + 2) * 16, kk);
    __builtin_amdgcn_s_barrier();
    asm volatile("s_waitcnt lgkmcnt(4)" ::: "memory");   // drains prev Ph4's 12 (aL,b01)
    __builtin_amdgcn_s_setprio(1);
#pragma unroll
    for (int kk = 0; kk < 2; ++kk)
#pragma unroll
      for (int m = 0; m < 4; ++m) {
        acc[m][0] = MFMA16(aL[m][kk], B01C[0][kk], acc[m][0]);
        acc[m][1] = MFMA16(aL[m][kk], B01C[1][kk], acc[m][1]);
      }
    __builtin_amdgcn_s_setprio(0);
    // ---- Ph2: issue aH(D) [8]; MFMA Q_D = acc[m0-3][n23] (aL x b23)
#pragma unroll
    for (int m = 0; m < 4; ++m)
#pragma unroll
      for (int kk = 0; kk < 2; ++kk) aH[m][kk] = FRA(D, (m + 4) * 16 + lc, kk);
    __builtin_amdgcn_s_barrier();
    asm volatile("s_waitcnt lgkmcnt(8)" ::: "memory");   // drains b23
    __builtin_amdgcn_s_setprio(1);
#pragma unroll
    for (int kk = 0; kk < 2; ++kk)
#pragma unroll
      for (int m = 0; m < 4; ++m) {
        acc[m][2] = MFMA16(aL[m][kk], b23v[0][kk], acc[m][2]);
        acc[m][3] = MFMA16(aL[m][kk], b23v[1][kk], acc[m][3]);
      }
    __builtin_amdgcn_s_setprio(0);
    // ---- Ph3: stage SA(T+2); vmcnt confirms tile T+1; MFMA Q_C = acc[m4-7][n23]
    if (T + 2 < NT) {
      SA(T + 2, 0); SA(T + 2, 1);
      asm volatile("s_waitcnt vmcnt(4)" ::: "memory");   // T+1's 8 landed, SA(T+2) in flight
    } else {
      asm volatile("s_waitcnt vmcnt(0)" ::: "memory");
    }
    __builtin_amdgcn_s_barrier();                        // all waves' T+1 data visible
    asm volatile("s_waitcnt lgkmcnt(0)" ::: "memory");   // drains aH
    __builtin_amdgcn_s_setprio(1);
#pragma unroll
    for (int kk = 0; kk < 2; ++kk)
#pragma unroll
      for (int m = 0; m < 4; ++m) {
        acc[4 + m][2] = MFMA16(aH[m][kk], b23v[0][kk], acc[4 + m][2]);
        acc[4 + m][3] = MFMA16(aH[m][kk], b23v[1][kk], acc[4 + m][3]);
      }
    __builtin_amdgcn_s_setprio(0);
    // ---- Ph4: issue next-tile b01(D^1)[4] + aL(D^1)[8]; stage SB(T+2); MFMA Q_B
    if (T + 1 < NT) {
#pragma unroll
      for (int n = 0; n < 2; ++n)
#pragma unroll
        for (int kk = 0; kk < 2; ++kk) B01N[n][kk] = FRB((D) ^ 1, brl + n * 16, kk);
#pragma unroll
      for (int m = 0; m < 4; ++m)
#pragma unroll
        for (int kk = 0; kk < 2; ++kk) aL[m][kk] = FRA((D) ^ 1, m * 16 + lc, kk);
    }
    if (T + 2 < NT) { SB(T + 2, 0); SB(T + 2, 1); }
    __builtin_amdgcn_s_barrier();
    if (T + 1 < NT) asm volatile("s_waitcnt lgkmcnt(12)" ::: "memory");  // keep 12 in flight
    __builtin_amdgcn_s_setprio(1);
#pragma unroll
    for (int kk = 0; kk < 2; ++kk)
#pragma unroll
      for (int m = 0; m < 4; ++m) {
        acc[4 + m][0] = MFMA16(aH[m][kk], B01C[0][kk], acc[4 + m][0]);
        acc[4 + m][1] = MFMA16(aH[m][kk], B01C[1][kk], acc[4 + m][1]);
      }
    __builtin_amdgcn_s_setprio(0);
  };

  for (int k = 0; k < (NT >> 1); ++k) {
    tile_body(2 * k,     0, b01A, b01B);
    tile_body(2 * k + 1, 1, b01B, b01A);
  }
#undef FRA
#undef FRB
  // ---- epilogue: per-wave LDS staging -> coalesced vector stores
  char* W = lds + wid * 16384;
  if (EPI & 8) {
    bf16_t* Wb = (bf16_t*)W;
    bf16_t* Cbz = Cb + (size_t)blockIdx.z * splitStride;
#pragma unroll
    for (int mc = 0; mc < 2; ++mc) {
#pragma unroll
      for (int m4 = 0; m4 < 4; ++m4) {
#pragma unroll
        for (int n = 0; n < 4; ++n) {
          const int col = bn + wc * 64 + n * 16 + lc;
          float bv = (EPI & 1) ? bias[col] : 0.f;
#pragma unroll
          for (int i = 0; i < 4; ++i) {
            float v = acc[mc * 4 + m4][n][i];
            if (EPI & 1) v += bv;
            if (EPI & 2) v = 0.5f * v * (1.f + tanhf(0.7978845608028654f * (v + 0.044715f * v * v * v)));
            Wb[(m4 * 16 + lg * 4 + i) * 72 + n * 16 + lc] = bf16_t(v);
          }
        }
      }
      asm volatile("s_waitcnt lgkmcnt(0)" ::: "memory");
      __builtin_amdgcn_sched_barrier(0);
#pragma unroll
      for (int p = 0; p < 8; ++p) {
        const int rl = p * 8 + (lane >> 3), j = lane & 7;
        uint4 v = *(const uint4*)&Wb[rl * 72 + j * 8];
        const int grow = bm + wr * 128 + mc * 64 + rl;
        const int gcol = bn + wc * 64 + j * 8;
        *(uint4*)&Cbz[(size_t)grow * N + gcol] = v;
      }
      asm volatile("s_waitcnt lgkmcnt(0)" ::: "memory");
      __builtin_amdgcn_sched_barrier(0);
    }
  } else {
    float* Wf = (float*)W;
    float* Cfz = Cf + (size_t)blockIdx.z * splitStride;
#pragma unroll
    for (int mc = 0; mc < 4; ++mc) {
#pragma unroll
      for (int m2 = 0; m2 < 2; ++m2) {
#pragma unroll
        for (int n = 0; n < 4; ++n) {
          const int col = bn + wc * 64 + n * 16 + lc;
          float bv = (EPI & 1) ? bias[col] : 0.f;
#pragma unroll
          for (int i = 0; i < 4; ++i) {
            float v = acc[mc * 2 + m2][n][i];
            if (EPI & 1) v += bv;
            if (EPI & 2) v = 0.5f * v * (1.f + tanhf(0.7978845608028654f * (v + 0.044715f * v * v * v)));
            Wf[(m2 * 16 + lg * 4 + i) * 72 + n * 16 + lc] = v;
          }
        }
      }
      asm volatile("s_waitcnt lgkmcnt(0)" ::: "memory");
      __builtin_amdgcn_sched_barrier(0);
#pragma unroll
      for (int p = 0; p < 8; ++p) {
        const int rl = p * 4 + (lane >> 4), j = lane & 15;
        float4 v = *(const float4*)&Wf[rl * 72 + j * 4];
        const int grow = bm + wr * 128 + mc * 32 + rl;
        const int gcol = bn + wc * 64 + j * 4;
        *(float4*)&Cfz[(size_t)grow * N + gcol] = v;
      }
      asm volatile("s_waitcnt lgkmcnt(0)" ::: "memory");
      __builtin_amdgcn_sched_barrier(0);
    }
  }
}

// ---------- split-K f32 partial reduction ----------
template <int NP, bool ADDIN, bool BIAS>
__global__ __launch_bounds__(256) void reduceP(const float* __restrict__ p0,
    const float* __restrict__ p1, const float* __restrict__ p2,
    const float* __restrict__ p3, const float* __restrict__ bias,
    float* __restrict__ out, int total, int colmask) {
  const int i = (blockIdx.x * 256 + threadIdx.x) * 4;
  if (i >= total) return;
  float4 v = *(const float4*)(p0 + i);
  float4 w = *(const float4*)(p1 + i);
  v.x += w.x; v.y += w.y; v.z += w.z; v.w += w.w;
  if (NP == 4) {
    float4 u = *(const float4*)(p2 + i);
    float4 z = *(const float4*)(p3 + i);
    v.x += u.x + z.x; v.y += u.y + z.y; v.z += u.z + z.z; v.w += u.w + z.w;
  }
  if (BIAS) {
    float4 b = *(const float4*)(bias + (i & colmask));
    v.x += b.x; v.y += b.y; v.z += b.z; v.w += b.w;
  }
  if (ADDIN) {
    float4 o = *(const float4*)(out + i);
    v.x += o.x; v.y += o.y; v.z += o.z; v.w += o.w;
  }
  *(float4*)(out + i) = v;
}

// ---------- split-K bf16 partial reduction (4 parts) -> f32 out ----------
__global__ __launch_bounds__(256) void reduce4b(const bf16_t* __restrict__ p0,
    const bf16_t* __restrict__ p1, const bf16_t* __restrict__ p2,
    const bf16_t* __restrict__ p3, float* __restrict__ out, int total) {
  const int i = (blockIdx.x * 256 + threadIdx.x) * 8;
  if (i >= total) return;
  uint4 a0 = *(const uint4*)(p0 + i);
  uint4 a1 = *(const uint4*)(p1 + i);
  uint4 a2 = *(const uint4*)(p2 + i);
  uint4 a3 = *(const uint4*)(p3 + i);
  const unsigned* u0 = (const unsigned*)&a0;
  const unsigned* u1 = (const unsigned*)&a1;
  const unsigned* u2 = (const unsigned*)&a2;
  const unsigned* u3 = (const unsigned*)&a3;
  float r[8];
#pragma unroll
  for (int j = 0; j < 8; ++j) {
    const int w = j >> 1, sh = (j & 1) * 16;
    r[j] = bf2f((u0[w] >> sh) & 0xffffu) + bf2f((u1[w] >> sh) & 0xffffu) +
           bf2f((u2[w] >> sh) & 0xffffu) + bf2f((u3[w] >> sh) & 0xffffu);
  }
  *(float4*)(out + i) = make_float4(r[0], r[1], r[2], r[3]);
  *(float4*)(out + i + 4) = make_float4(r[4], r[5], r[6], r[7]);
}

// ---------- RoPE + head split ----------
__global__ __launch_bounds__(128) void rope_kernel(const bf16_t* __restrict__ qkv,
    bf16_t* __restrict__ qh, bf16_t* __restrict__ kh, bf16_t* __restrict__ vT) {
  const int n = blockIdx.x, hh = blockIdx.y;
  const int d = threadIdx.x;
  const int mp = hh >> 2, hi = hh & 3;
  const bf16_t* row = qkv + (size_t)n * 6144 + mp * 1536 + hi * 128;  // [q|v|k] each 512 per mp
  float q = __bfloat162float(row[d]);
  float k = __bfloat162float(row[1024 + d]);
  if (d < 64) {  // wave-uniform branch
    const float ang = (float)n * powf(10000.f, -(float)(d & ~1) / 64.f);
    const float sn = sinf(ang), cs = cosf(ang);
    const float qp = __shfl_xor(q, 1), kp = __shfl_xor(k, 1);
    if (d & 1) { q = q * cs + qp * sn; k = k * cs + kp * sn; }
    else       { q = q * cs - qp * sn; k = k * cs - kp * sn; }
  }
  qh[((size_t)hh * 2048 + n) * 128 + d] = bf16_t(q * 0.08838834764831845f); // 1/sqrt(128)
  kh[((size_t)hh * 2048 + n) * 128 + d] = bf16_t(k);
  vT[((size_t)hh * 128 + d) * 2048 + n] = row[512 + d];
}

// ---------- causal flash attention, pairs + KV-split(z=3), partial (O,m,l) output ----------
__global__ __launch_bounds__(256) void attn_kernel(const bf16_t* __restrict__ qh,
    const bf16_t* __restrict__ kh, const bf16_t* __restrict__ vT,
    bf16_t* __restrict__ Op, float2* __restrict__ ml) {
  __shared__ alignas(16) char Kbuf[2][16384];    // [kv 64][d 128] bf16, chunk ^= row&15
  __shared__ alignas(16) char Vbuf[2][16384];    // [d 128][kv 64] bf16, chunk ^= row&7
  __shared__ alignas(16) bf16_t Ps[4][16 * 72];  // per-wave P, stride 72
  const int p = blockIdx.x, h = blockIdx.y, z = blockIdx.z;
  const int tid = threadIdx.x, wid = tid >> 6, lane = tid & 63;
  const int lc = lane & 15, lg = lane >> 4;
  const int krow = wid * 4 + (lane >> 4);
  const int vrow = wid * 8 + (lane >> 3);

  auto stage = [&](int kv0, int d) {
#pragma unroll
    for (int i = 0; i < 4; ++i) {
      const int kr = i * 16 + krow;
      const int kch = (lane & 15) ^ (kr & 15);
      gload_lds16(kh + ((size_t)h * 2048 + kv0 + kr) * 128 + kch * 8,
                  Kbuf[d] + i * 4096 + wid * 1024);
      const int vr = i * 32 + vrow;
      const int vch = (lane & 7) ^ (vr & 7);
      gload_lds16(vT + ((size_t)h * 128 + vr) * 2048 + kv0 + vch * 8,
                  Vbuf[d] + i * 4096 + wid * 1024);
    }
  };
#define FRK(d, row, ch) (*(const bfrag*)(Kbuf[d] + (row) * 256 + (((ch) ^ ((row) & 15)) << 4)))
#define FRV(d, row, ch) (*(const bfrag*)(Vbuf[d] + (row) * 128 + (((ch) ^ ((row) & 7)) << 4)))

#pragma unroll 1
  for (int half = 0; half < 2; ++half) {
    const int qt = half ? (31 - p) : p;
    const int nkv = qt + 1;
    const int lo = (z * nkv) / 3, hi = ((z + 1) * nkv) / 3;
    const int nj = hi - lo;
    const int qr = qt * 64 + wid * 16;
    const bf16_t* Qb = qh + ((size_t)h * 2048 + qr) * 128;
    bfrag qf[4];
#pragma unroll
    for (int ks = 0; ks < 4; ++ks)
      qf[ks] = *(const bfrag*)&Qb[lc * 128 + ks * 32 + lg * 8];
    f32x4 O[8] = {};
    float mr[4] = {-1e30f, -1e30f, -1e30f, -1e30f};
    float lsum[4] = {0.f, 0.f, 0.f, 0.f};

    if (nj > 0) {
      stage(lo * 64, 0);
      asm volatile("s_waitcnt vmcnt(0)" ::: "memory");
      __builtin_amdgcn_s_barrier();
    }
#pragma unroll 1
    for (int j = 0; j < nj; ++j) {
      const int kt = lo + j, d = j & 1;
      const int kv0 = kt * 64;
      if (j + 1 < nj) stage(kv0 + 64, d ^ 1);  // overlap with compute
      f32x4 s[4];
#pragma unroll
      for (int c = 0; c < 4; ++c) {
        f32x4 a = {};
#pragma unroll
        for (int ks = 0; ks < 4; ++ks) {
          bfrag kf = FRK(d, c * 16 + lc, ks * 4 + lg);
          a = MFMA16(qf[ks], kf, a);
        }
        s[c] = a;
      }
      if (kt == qt) {  // diagonal tile: causal mask
#pragma unroll
        for (int c = 0; c < 4; ++c)
#pragma unroll
          for (int i = 0; i < 4; ++i)
            if (kv0 + c * 16 + lc > qr + lg * 4 + i) s[c][i] = -1e10f;
      }
      float pm[4];
#pragma unroll
      for (int i = 0; i < 4; ++i)
        pm[i] = fmaxf(fmaxf(s[0][i], s[1][i]), fmaxf(s[2][i], s[3][i]));
#pragma unroll
      for (int m = 1; m < 16; m <<= 1)
#pragma unroll
        for (int i = 0; i < 4; ++i) pm[i] = fmaxf(pm[i], __shfl_xor(pm[i], m));
      float al[4], rs[4];
#pragma unroll
      for (int i = 0; i < 4; ++i) {
        const float mn = fmaxf(mr[i], pm[i]);
        al[i] = __expf(mr[i] - mn);
        mr[i] = mn;
        rs[i] = 0.f;
      }
#pragma unroll
      for (int c = 0; c < 4; ++c)
#pragma unroll
        for (int i = 0; i < 4; ++i) {
          const float pv = __expf(s[c][i] - mr[i]);
          s[c][i] = pv; rs[i] += pv;
        }
#pragma unroll
      for (int m = 1; m < 16; m <<= 1)
#pragma unroll
        for (int i = 0; i < 4; ++i) rs[i] += __shfl_xor(rs[i], m);
#pragma unroll
      for (int i = 0; i < 4; ++i) lsum[i] = lsum[i] * al[i] + rs[i];
#pragma unroll
      for (int n = 0; n < 8; ++n)
#pragma unroll
        for (int i = 0; i < 4; ++i) O[n][i] *= al[i];
#pragma unroll
      for (int c = 0; c < 4; ++c)
#pragma unroll
        for (int i = 0; i < 4; ++i)
          Ps[wid][(lg * 4 + i) * 72 + c * 16 + lc] = bf16_t(s[c][i]);
#pragma unroll
      for (int k2 = 0; k2 < 2; ++k2) {
        bfrag pf = *(const bfrag*)((const char*)&Ps[wid][0] + lc * 144 + k2 * 64 + lg * 16);
#pragma unroll
        for (int n = 0; n < 8; ++n) {
          bfrag vf = FRV(d, n * 16 + lc, k2 * 4 + lg);
          O[n] = MFMA16(pf, vf, O[n]);
        }
      }
      if (j + 1 < nj) asm volatile("s_waitcnt vmcnt(0)" ::: "memory");
      asm volatile("s_waitcnt lgkmcnt(0)" ::: "memory");
      __builtin_amdgcn_s_barrier();
    }
    const size_t rb = (size_t)(z * 16 + h) * 2048 + qr;
#pragma unroll
    for (int n = 0; n < 8; ++n)
#pragma unroll
      for (int i = 0; i < 4; ++i)
        Op[(rb + lg * 4 + i) * 128 + n * 16 + lc] = bf16_t(O[n][i]);
    if (lc == 0) {
#pragma unroll
      for (int i = 0; i < 4; ++i)
        ml[rb + lg * 4 + i] = make_float2(mr[i], lsum[i]);
    }
    __builtin_amdgcn_s_barrier();
  }
#undef FRK
#undef FRV
}

// ---------- combine z=3 attention partials -> av bf16 [2048][2048] ----------
__global__ __launch_bounds__(256) void attn_combine(const bf16_t* __restrict__ Op,
    const float2* __restrict__ ml, bf16_t* __restrict__ av) {
  const int idx = blockIdx.x * 256 + threadIdx.x;
  const int t = idx & 15, hr = idx >> 4;
  const int ZS = 16 * 2048;
  const size_t ZO = (size_t)ZS * 128;
  const float2 m0 = ml[hr], m1 = ml[ZS + hr], m2 = ml[2 * ZS + hr];
  const float M = fmaxf(fmaxf(m0.x, m1.x), m2.x);
  const float w0 = __expf(m0.x - M), w1 = __expf(m1.x - M), w2 = __expf(m2.x - M);
  const float inv = 1.f / (w0 * m0.y + w1 * m1.y + w2 * m2.y);
  const bf16_t* p0 = Op + (size_t)hr * 128 + t * 8;
  uint4 a0 = *(const uint4*)p0;
  uint4 a1 = *(const uint4*)(p0 + ZO);
  uint4 a2 = *(const uint4*)(p0 + 2 * ZO);
  const unsigned* u0 = (const unsigned*)&a0;
  const unsigned* u1 = (const unsigned*)&a1;
  const unsigned* u2 = (const unsigned*)&a2;
  bf16_t ov[8];
#pragma unroll
  for (int j = 0; j < 8; ++j) {
    const int w = j >> 1, sh = (j & 1) * 16;
    ov[j] = bf16_t((w0 * bf2f((u0[w] >> sh) & 0xffffu) +
                    w1 * bf2f((u1[w] >> sh) & 0xffffu) +
                    w2 * bf2f((u2[w] >> sh) & 0xffffu)) * inv);
  }
  const int row = hr & 2047, hh = hr >> 11;
  *(uint4*)(av + (size_t)row * 2048 + hh * 128 + t * 8) = *(const uint4*)ov;
}

extern "C" void kernel_launch(void* const* d_in, const int* in_sizes, int n_in,
                              void* d_out, int out_size, void* d_ws, size_t ws_size,
                              hipStream_t stream) {
  const float* x        = (const float*)d_in[0];
  const float* ln_scale = (const float*)d_in[1];
  const float* ln_offset= (const float*)d_in[2];
  const float* w_qkv    = (const float*)d_in[3];   // [2048][6144]
  const float* w_ao     = (const float*)d_in[4];   // [2048][2048]
  const float* w_ff_in  = (const float*)d_in[5];   // [2048][8192]
  const float* b_ff_in  = (const float*)d_in[6];   // [8192]
  const float* w_ff_out = (const float*)d_in[7];   // [8192][2048]
  const float* b_ff_out = (const float*)d_in[8];   // [2048]
  float* out = (float*)d_out;

  char* ws = (char*)d_ws;
  bf16_t* wqkvT   = (bf16_t*)(ws);                  // [6144][2048]; dead after qkv GEMM
  bf16_t* waoT    = (bf16_t*)(ws + 25165824);       // [2048][2048]
  bf16_t* wffinT  = (bf16_t*)(ws + 33554432);       // [8192][2048]
  bf16_t* wffoutT = (bf16_t*)(ws + 67108864);       // [2048][8192]
  bf16_t* h       = (bf16_t*)(ws + 100663296);      // [2048][2048]
  bf16_t* qhb     = (bf16_t*)(ws + 109051904);      // [16][2048][128]
  bf16_t* khb     = (bf16_t*)(ws + 117440512);
  bf16_t* vTb     = (bf16_t*)(ws + 125829120);      // [16][128][2048]
  bf16_t* avb     = (bf16_t*)(ws + 134217728);      // [2048][2048]
  bf16_t* qkvb    = (bf16_t*)(ws + 142606336);      // [2048][6144]; later pab / ff1
  bf16_t* ff1b    = qkvb;
  bf16_t* pab     = qkvb;                           // attn_out bf16 partials 4x[2048][2048]
  float*  pf      = (float*)(ws);                   // ff_out f32 partials (dead weights)
  bf16_t* Opart   = (bf16_t*)(ws);                  // attn partials 3x[16][2048][128] bf16
  float2* mlpart  = (float2*)(ws + 167772160);      // 3x[16][2048] float2

  hipFuncSetAttribute((const void*)gemm8p<0>,  hipFuncAttributeMaxDynamicSharedMemorySize, 131072);
  hipFuncSetAttribute((const void*)gemm8p<8>,  hipFuncAttributeMaxDynamicSharedMemorySize, 131072);
  hipFuncSetAttribute((const void*)gemm8p<11>, hipFuncAttributeMaxDynamicSharedMemorySize, 131072);

  dim3 b256(256), b512(512);
  transpose_cvt<<<dim3(96, 32),  b256, 0, stream>>>(w_qkv,    wqkvT,   2048, 6144);
  transpose_cvt<<<dim3(32, 32),  b256, 0, stream>>>(w_ao,     waoT,    2048, 2048);
  transpose_cvt<<<dim3(128, 32), b256, 0, stream>>>(w_ff_in,  wffinT,  2048, 8192);
  transpose_cvt<<<dim3(32, 128), b256, 0, stream>>>(w_ff_out, wffoutT, 8192, 2048);
  ln_kernel<<<dim3(2048), b256, 0, stream>>>(x, ln_scale, ln_offset, h);

  gemm8p<8><<<dim3(24, 8, 1), b512, 131072, stream>>>(h, 2048, wqkvT, 2048,
      nullptr, nullptr, qkvb, 2048, 6144, 2048, 0);
  rope_kernel<<<dim3(2048, 16), dim3(128), 0, stream>>>(qkvb, qhb, khb, vTb);

  attn_kernel<<<dim3(16, 16, 3), b256, 0, stream>>>(qhb, khb, vTb, Opart, mlpart);
  attn_combine<<<dim3(2048), b256, 0, stream>>>(Opart, mlpart, avb);

  // attn_out: split-K=4 (K=512 each), bf16 partials in dead qkvb region
  gemm8p<8><<<dim3(8, 8, 4), b512, 131072, stream>>>(avb, 2048, waoT, 2048,
      nullptr, nullptr, pab, 2048, 2048, 512, (size_t)2048 * 2048);
  reduce4b<<<dim3(2048), b256, 0, stream>>>(pab, pab + 4194304, pab + 2 * 4194304,
      pab + 3 * 4194304, out, 4194304);

  gemm8p<11><<<dim3(32, 8, 1), b512, 131072, stream>>>(h, 2048, wffinT, 2048,
      b_ff_in, nullptr, ff1b, 2048, 8192, 2048, 0);

  // ff_out: split-K=4 (K=2048 each), f32 partials over dead weight region
  gemm8p<0><<<dim3(8, 8, 4), b512, 131072, stream>>>(ff1b, 8192, wffoutT, 8192,
      nullptr, pf, nullptr, 2048, 2048, 2048, (size_t)2048 * 2048);
  reduceP<4, true, true><<<dim3(4096), b256, 0, stream>>>(pf, pf + 4194304,
      pf + 2 * 4194304, pf + 3 * 4194304, b_ff_out, out, 4194304, 2047);
}

// Round 10
// 412.518 us; speedup vs baseline: 2.2270x; 2.2270x over previous
//
#include <hip/hip_runtime.h>
#include <hip/hip_bf16.h>

using bf16_t = __hip_bfloat16;
typedef __attribute__((ext_vector_type(8))) __bf16 bfrag;   // 8 bf16 = 4 VGPR (MFMA A/B operand)
typedef __attribute__((ext_vector_type(4))) float f32x4;    // MFMA C/D operand

#define MFMA16(a, b, c) __builtin_amdgcn_mfma_f32_16x16x32_bf16((a), (b), (c), 0, 0, 0)

__device__ __forceinline__ void gload_lds16(const void* g, void* l) {
  // async global->LDS, 16B/lane; LDS dest = wave-uniform base + lane*16
  __builtin_amdgcn_global_load_lds((const __attribute__((address_space(1))) void*)g,
                                   (__attribute__((address_space(3))) void*)l, 16, 0, 0);
}

__device__ __forceinline__ float bf2f(unsigned u) { return __uint_as_float(u << 16); }

// ---------- fused weight transpose + f32->bf16 convert (all 4 weights, one launch) ----------
// in[K][N] f32 -> out[N][K] bf16, 64x64 tiles.
__global__ __launch_bounds__(256) void transpose_cvt4(
    const float* __restrict__ in0, bf16_t* __restrict__ out0,
    const float* __restrict__ in1, bf16_t* __restrict__ out1,
    const float* __restrict__ in2, bf16_t* __restrict__ out2,
    const float* __restrict__ in3, bf16_t* __restrict__ out3) {
  __shared__ float t[64][65];
  int b = blockIdx.x;
  const float* in; bf16_t* out; int K, N, nx;
  if (b < 3072)      { in = in0; out = out0; K = 2048; N = 6144; nx = 96; }
  else if (b < 4096) { in = in1; out = out1; K = 2048; N = 2048; nx = 32; b -= 3072; }
  else if (b < 8192) { in = in2; out = out2; K = 2048; N = 8192; nx = 128; b -= 4096; }
  else               { in = in3; out = out3; K = 8192; N = 2048; nx = 32; b -= 8192; }
  const int n0 = (b % nx) * 64, k0 = (b / nx) * 64;
  const int tx = threadIdx.x & 15, ty = threadIdx.x >> 4;   // 16 x 16
#pragma unroll
  for (int i = 0; i < 4; ++i) {
    float4 v = *(const float4*)&in[(size_t)(k0 + i * 16 + ty) * N + n0 + tx * 4];
    t[i * 16 + ty][tx * 4 + 0] = v.x; t[i * 16 + ty][tx * 4 + 1] = v.y;
    t[i * 16 + ty][tx * 4 + 2] = v.z; t[i * 16 + ty][tx * 4 + 3] = v.w;
  }
  __syncthreads();
#pragma unroll
  for (int i = 0; i < 4; ++i) {
    const int n = i * 16 + ty;
    bf16_t w[4];
#pragma unroll
    for (int j = 0; j < 4; ++j) w[j] = bf16_t(t[tx * 4 + j][n]);
    *(uint2*)&out[(size_t)(n0 + n) * K + k0 + tx * 4] = *(const uint2*)w;
  }
}

// ---------- LayerNorm: x f32 [2048][2048] -> h bf16 ----------
__global__ __launch_bounds__(256) void ln_kernel(const float* __restrict__ x,
    const float* __restrict__ sc, const float* __restrict__ of, bf16_t* __restrict__ h) {
  __shared__ float red[8];
  const int n = blockIdx.x, tid = threadIdx.x;
  const float* xr = x + (size_t)n * 2048;
  float4 a = ((const float4*)xr)[tid * 2];
  float4 b = ((const float4*)xr)[tid * 2 + 1];
  float s = a.x + a.y + a.z + a.w + b.x + b.y + b.z + b.w;
  float q = a.x * a.x + a.y * a.y + a.z * a.z + a.w * a.w +
            b.x * b.x + b.y * b.y + b.z * b.z + b.w * b.w;
#pragma unroll
  for (int m = 32; m; m >>= 1) { s += __shfl_xor(s, m); q += __shfl_xor(q, m); }
  if ((tid & 63) == 0) { red[(tid >> 6) * 2] = s; red[(tid >> 6) * 2 + 1] = q; }
  __syncthreads();
  s = red[0] + red[2] + red[4] + red[6];
  q = red[1] + red[3] + red[5] + red[7];
  const float mu = s * (1.f / 2048.f);
  const float inv = rsqrtf(q * (1.f / 2048.f) - mu * mu + 1e-5f);
  const int base = tid * 8;
  float v[8] = {a.x, a.y, a.z, a.w, b.x, b.y, b.z, b.w};
  bf16_t* hr = h + (size_t)n * 2048 + base;
#pragma unroll
  for (int j = 0; j < 8; ++j) hr[j] = bf16_t((v[j] - mu) * inv * sc[base + j] + of[base + j]);
}

// ---------- m201-style 8-phase 256x256 GEMM (R8-proven): C = A*BT^T ----------
// 8 phases / 2 K-tiles; reads 12/4/8/0 per phase; vmcnt(4) at ph4/ph8 only.
// EPI bits: 1=+bias, 2=gelu, 8=store bf16 (else f32)
template <int EPI>
__global__ __launch_bounds__(512, 2) void gemm8p(
    const bf16_t* __restrict__ A, int lda, const bf16_t* __restrict__ BT, int ldb,
    const float* __restrict__ bias, float* __restrict__ Cf, bf16_t* __restrict__ Cb,
    int M, int N, int K, size_t splitStride) {
  extern __shared__ __align__(16) char lds[];   // 128 KiB
  const int tid = threadIdx.x, wid = tid >> 6, lane = tid & 63;
  const int lc = lane & 15, lg = lane >> 4;
  const int bm = blockIdx.y * 256, bn = blockIdx.x * 256;
  const int wr = wid >> 2, wc = wid & 3;              // 2M x 4N waves, each 128x64 out
  const int NT = K >> 6, niter = NT >> 1;             // NT even
  const int srow = tid >> 3;
  const int scol = (((tid & 7) ^ ((tid >> 3) & 7)) << 3);
  const bf16_t* Abase = A + (size_t)blockIdx.z * K + (size_t)(bm + srow) * lda + scol;
  const bf16_t* Bbase = BT + (size_t)blockIdx.z * K + (size_t)(bn + srow) * ldb + scol;
  auto SA = [&](int T, int h) {
    char* dst = lds + (T & 1) * 32768 + h * 16384 + wid * 1024;
    const bf16_t* src = Abase + (size_t)(h * 128) * lda + T * 64;
    gload_lds16(src, dst); gload_lds16(src + (size_t)64 * lda, dst + 8192);
  };
  auto SB = [&](int T, int h) {
    char* dst = lds + 65536 + (T & 1) * 32768 + h * 16384 + wid * 1024;
    const bf16_t* src = Bbase + (size_t)(h * 128) * ldb + T * 64;
    gload_lds16(src, dst); gload_lds16(src + (size_t)64 * ldb, dst + 8192);
  };
#define FRA(d, row, kk) (*(const bfrag*)(lds + (d) * 32768 + wr * 16384 + (row) * 128 + \
    ((((kk) * 4 + lg) ^ ((row) & 7)) << 4)))
#define FRB(d, row, kk) (*(const bfrag*)(lds + 65536 + (d) * 32768 + (wc >> 1) * 16384 + \
    (row) * 128 + ((((kk) * 4 + lg) ^ ((row) & 7)) << 4)))
#define PHASE_SYNC() do { __builtin_amdgcn_s_barrier(); \
    asm volatile("s_waitcnt lgkmcnt(0)" ::: "memory"); \
    __builtin_amdgcn_sched_barrier(0); __builtin_amdgcn_s_setprio(1); } while (0)
#define PHASE_END() do { __builtin_amdgcn_s_setprio(0); __builtin_amdgcn_s_barrier(); } while (0)
#define PHASE_END_VM(lastf) do { __builtin_amdgcn_s_setprio(0); \
    if (lastf) asm volatile("s_waitcnt vmcnt(0)" ::: "memory"); \
    else       asm volatile("s_waitcnt vmcnt(4)" ::: "memory"); \
    __builtin_amdgcn_s_barrier(); } while (0)

  // prologue: tile0 all 4 halves + tile1 B halves
  SB(0, 0); SB(0, 1); SA(0, 0); SA(0, 1); SB(1, 0); SB(1, 1);
  asm volatile("s_waitcnt vmcnt(4)" ::: "memory");    // tile0 landed
  __builtin_amdgcn_s_barrier();

  f32x4 acc[8][4] = {};
  const int brl = (wc & 1) * 64 + lc;                 // B local row base (+n*16)

  for (int k = 0; k < niter; ++k) {
    const int T1 = 2 * k + 1, T2 = 2 * k + 2, T3 = 2 * k + 3;
    const bool last = (k == niter - 1);
    bfrag aq[4][2], b01[2][2], b23[2][2];
#pragma unroll 1
    for (int d = 0; d < 2; ++d) {                     // d=0: phases 1-4, d=1: phases 5-8
      // ---- phase 1/5: read a0-quad + b01; stage SA(T1,0) / SA(T2,0)
#pragma unroll
      for (int m = 0; m < 4; ++m)
#pragma unroll
        for (int kk = 0; kk < 2; ++kk) aq[m][kk] = FRA(d, m * 16 + lc, kk);
#pragma unroll
      for (int n = 0; n < 2; ++n)
#pragma unroll
        for (int kk = 0; kk < 2; ++kk) b01[n][kk] = FRB(d, brl + n * 16, kk);
      if (d == 0) SA(T1, 0); else if (!last) SA(T2, 0);
      PHASE_SYNC();
#pragma unroll
      for (int kk = 0; kk < 2; ++kk)
#pragma unroll
        for (int m = 0; m < 4; ++m) {
          acc[m][0] = MFMA16(aq[m][kk], b01[0][kk], acc[m][0]);
          acc[m][1] = MFMA16(aq[m][kk], b01[1][kk], acc[m][1]);
        }
      PHASE_END();
      // ---- phase 2/6: read b23; stage SA(T1,1) / SA(T2,1)
#pragma unroll
      for (int n = 0; n < 2; ++n)
#pragma unroll
        for (int kk = 0; kk < 2; ++kk) b23[n][kk] = FRB(d, brl + (n + 2) * 16, kk);
      if (d == 0) SA(T1, 1); else if (!last) SA(T2, 1);
      PHASE_SYNC();
#pragma unroll
      for (int kk = 0; kk < 2; ++kk)
#pragma unroll
        for (int m = 0; m < 4; ++m) {
          acc[m][2] = MFMA16(aq[m][kk], b23[0][kk], acc[m][2]);
          acc[m][3] = MFMA16(aq[m][kk], b23[1][kk], acc[m][3]);
        }
      PHASE_END();
      // ---- phase 3/7: read a1-quad; stage SB(T2,0) / SB(T3,0)
#pragma unroll
      for (int m = 0; m < 4; ++m)
#pragma unroll
        for (int kk = 0; kk < 2; ++kk) aq[m][kk] = FRA(d, (m + 4) * 16 + lc, kk);
      if (!last) { if (d == 0) SB(T2, 0); else SB(T3, 0); }
      PHASE_SYNC();
#pragma unroll
      for (int kk = 0; kk < 2; ++kk)
#pragma unroll
        for (int m = 0; m < 4; ++m) {
          acc[4 + m][2] = MFMA16(aq[m][kk], b23[0][kk], acc[4 + m][2]);
          acc[4 + m][3] = MFMA16(aq[m][kk], b23[1][kk], acc[4 + m][3]);
        }
      PHASE_END();
      // ---- phase 4/8: no reads; stage SB(T2,1) / SB(T3,1); counted vmcnt
      if (!last) { if (d == 0) SB(T2, 1); else SB(T3, 1); }
      PHASE_SYNC();
#pragma unroll
      for (int kk = 0; kk < 2; ++kk)
#pragma unroll
        for (int m = 0; m < 4; ++m) {
          acc[4 + m][0] = MFMA16(aq[m][kk], b01[0][kk], acc[4 + m][0]);
          acc[4 + m][1] = MFMA16(aq[m][kk], b01[1][kk], acc[4 + m][1]);
        }
      PHASE_END_VM(last);
    }
  }
#undef FRA
#undef FRB
#undef PHASE_SYNC
#undef PHASE_END
#undef PHASE_END_VM
  // ---- epilogue: per-wave LDS staging -> coalesced vector stores
  char* W = lds + wid * 16384;
  if (EPI & 8) {
    bf16_t* Wb = (bf16_t*)W;
    bf16_t* Cbz = Cb + (size_t)blockIdx.z * splitStride;
#pragma unroll
    for (int mc = 0; mc < 2; ++mc) {
#pragma unroll
      for (int m4 = 0; m4 < 4; ++m4) {
#pragma unroll
        for (int n = 0; n < 4; ++n) {
          const int col = bn + wc * 64 + n * 16 + lc;
          float bv = (EPI & 1) ? bias[col] : 0.f;
#pragma unroll
          for (int i = 0; i < 4; ++i) {
            float v = acc[mc * 4 + m4][n][i];
            if (EPI & 1) v += bv;
            if (EPI & 2) v = 0.5f * v * (1.f + tanhf(0.7978845608028654f * (v + 0.044715f * v * v * v)));
            Wb[(m4 * 16 + lg * 4 + i) * 72 + n * 16 + lc] = bf16_t(v);
          }
        }
      }
      asm volatile("s_waitcnt lgkmcnt(0)" ::: "memory");
      __builtin_amdgcn_sched_barrier(0);
#pragma unroll
      for (int p = 0; p < 8; ++p) {
        const int rl = p * 8 + (lane >> 3), j = lane & 7;
        uint4 v = *(const uint4*)&Wb[rl * 72 + j * 8];
        const int grow = bm + wr * 128 + mc * 64 + rl;
        const int gcol = bn + wc * 64 + j * 8;
        *(uint4*)&Cbz[(size_t)grow * N + gcol] = v;
      }
      asm volatile("s_waitcnt lgkmcnt(0)" ::: "memory");
      __builtin_amdgcn_sched_barrier(0);
    }
  } else {
    float* Wf = (float*)W;
    float* Cfz = Cf + (size_t)blockIdx.z * splitStride;
#pragma unroll
    for (int mc = 0; mc < 4; ++mc) {
#pragma unroll
      for (int m2 = 0; m2 < 2; ++m2) {
#pragma unroll
        for (int n = 0; n < 4; ++n) {
          const int col = bn + wc * 64 + n * 16 + lc;
          float bv = (EPI & 1) ? bias[col] : 0.f;
#pragma unroll
          for (int i = 0; i < 4; ++i) {
            float v = acc[mc * 2 + m2][n][i];
            if (EPI & 1) v += bv;
            if (EPI & 2) v = 0.5f * v * (1.f + tanhf(0.7978845608028654f * (v + 0.044715f * v * v * v)));
            Wf[(m2 * 16 + lg * 4 + i) * 72 + n * 16 + lc] = v;
          }
        }
      }
      asm volatile("s_waitcnt lgkmcnt(0)" ::: "memory");
      __builtin_amdgcn_sched_barrier(0);
#pragma unroll
      for (int p = 0; p < 8; ++p) {
        const int rl = p * 4 + (lane >> 4), j = lane & 15;
        float4 v = *(const float4*)&Wf[rl * 72 + j * 4];
        const int grow = bm + wr * 128 + mc * 32 + rl;
        const int gcol = bn + wc * 64 + j * 4;
        *(float4*)&Cfz[(size_t)grow * N + gcol] = v;
      }
      asm volatile("s_waitcnt lgkmcnt(0)" ::: "memory");
      __builtin_amdgcn_sched_barrier(0);
    }
  }
}

// ---------- split-K f32 partial reduction ----------
template <int NP, bool ADDIN, bool BIAS>
__global__ __launch_bounds__(256) void reduceP(const float* __restrict__ p0,
    const float* __restrict__ p1, const float* __restrict__ p2,
    const float* __restrict__ p3, const float* __restrict__ bias,
    float* __restrict__ out, int total, int colmask) {
  const int i = (blockIdx.x * 256 + threadIdx.x) * 4;
  if (i >= total) return;
  float4 v = *(const float4*)(p0 + i);
  float4 w = *(const float4*)(p1 + i);
  v.x += w.x; v.y += w.y; v.z += w.z; v.w += w.w;
  if (NP == 4) {
    float4 u = *(const float4*)(p2 + i);
    float4 z = *(const float4*)(p3 + i);
    v.x += u.x + z.x; v.y += u.y + z.y; v.z += u.z + z.z; v.w += u.w + z.w;
  }
  if (BIAS) {
    float4 b = *(const float4*)(bias + (i & colmask));
    v.x += b.x; v.y += b.y; v.z += b.z; v.w += b.w;
  }
  if (ADDIN) {
    float4 o = *(const float4*)(out + i);
    v.x += o.x; v.y += o.y; v.z += o.z; v.w += o.w;
  }
  *(float4*)(out + i) = v;
}

// ---------- split-K bf16 partial reduction (4 parts) -> f32 out ----------
__global__ __launch_bounds__(256) void reduce4b(const bf16_t* __restrict__ p0,
    const bf16_t* __restrict__ p1, const bf16_t* __restrict__ p2,
    const bf16_t* __restrict__ p3, float* __restrict__ out, int total) {
  const int i = (blockIdx.x * 256 + threadIdx.x) * 8;
  if (i >= total) return;
  uint4 a0 = *(const uint4*)(p0 + i);
  uint4 a1 = *(const uint4*)(p1 + i);
  uint4 a2 = *(const uint4*)(p2 + i);
  uint4 a3 = *(const uint4*)(p3 + i);
  const unsigned* u0 = (const unsigned*)&a0;
  const unsigned* u1 = (const unsigned*)&a1;
  const unsigned* u2 = (const unsigned*)&a2;
  const unsigned* u3 = (const unsigned*)&a3;
  float r[8];
#pragma unroll
  for (int j = 0; j < 8; ++j) {
    const int w = j >> 1, sh = (j & 1) * 16;
    r[j] = bf2f((u0[w] >> sh) & 0xffffu) + bf2f((u1[w] >> sh) & 0xffffu) +
           bf2f((u2[w] >> sh) & 0xffffu) + bf2f((u3[w] >> sh) & 0xffffu);
  }
  *(float4*)(out + i) = make_float4(r[0], r[1], r[2], r[3]);
  *(float4*)(out + i + 4) = make_float4(r[4], r[5], r[6], r[7]);
}

// ---------- RoPE + head split ----------
__global__ __launch_bounds__(128) void rope_kernel(const bf16_t* __restrict__ qkv,
    bf16_t* __restrict__ qh, bf16_t* __restrict__ kh, bf16_t* __restrict__ vT) {
  const int n = blockIdx.x, hh = blockIdx.y;
  const int d = threadIdx.x;
  const int mp = hh >> 2, hi = hh & 3;
  const bf16_t* row = qkv + (size_t)n * 6144 + mp * 1536 + hi * 128;  // [q|v|k] each 512 per mp
  float q = __bfloat162float(row[d]);
  float k = __bfloat162float(row[1024 + d]);
  if (d < 64) {  // wave-uniform branch
    const float ang = (float)n * powf(10000.f, -(float)(d & ~1) / 64.f);
    const float sn = sinf(ang), cs = cosf(ang);
    const float qp = __shfl_xor(q, 1), kp = __shfl_xor(k, 1);
    if (d & 1) { q = q * cs + qp * sn; k = k * cs + kp * sn; }
    else       { q = q * cs - qp * sn; k = k * cs - kp * sn; }
  }
  qh[((size_t)hh * 2048 + n) * 128 + d] = bf16_t(q * 0.08838834764831845f); // 1/sqrt(128)
  kh[((size_t)hh * 2048 + n) * 128 + d] = bf16_t(k);
  vT[((size_t)hh * 128 + d) * 2048 + n] = row[512 + d];
}

// ---------- causal flash attention, pairs + KV-split(z=3), partial (O,m,l) output ----------
__global__ __launch_bounds__(256) void attn_kernel(const bf16_t* __restrict__ qh,
    const bf16_t* __restrict__ kh, const bf16_t* __restrict__ vT,
    bf16_t* __restrict__ Op, float2* __restrict__ ml) {
  __shared__ alignas(16) char Kbuf[2][16384];    // [kv 64][d 128] bf16, chunk ^= row&15
  __shared__ alignas(16) char Vbuf[2][16384];    // [d 128][kv 64] bf16, chunk ^= row&7
  __shared__ alignas(16) bf16_t Ps[4][16 * 72];  // per-wave P, stride 72
  const int p = blockIdx.x, h = blockIdx.y, z = blockIdx.z;
  const int tid = threadIdx.x, wid = tid >> 6, lane = tid & 63;
  const int lc = lane & 15, lg = lane >> 4;
  const int krow = wid * 4 + (lane >> 4);
  const int vrow = wid * 8 + (lane >> 3);

  auto stage = [&](int kv0, int d) {
#pragma unroll
    for (int i = 0; i < 4; ++i) {
      const int kr = i * 16 + krow;
      const int kch = (lane & 15) ^ (kr & 15);
      gload_lds16(kh + ((size_t)h * 2048 + kv0 + kr) * 128 + kch * 8,
                  Kbuf[d] + i * 4096 + wid * 1024);
      const int vr = i * 32 + vrow;
      const int vch = (lane & 7) ^ (vr & 7);
      gload_lds16(vT + ((size_t)h * 128 + vr) * 2048 + kv0 + vch * 8,
                  Vbuf[d] + i * 4096 + wid * 1024);
    }
  };
#define FRK(d, row, ch) (*(const bfrag*)(Kbuf[d] + (row) * 256 + (((ch) ^ ((row) & 15)) << 4)))
#define FRV(d, row, ch) (*(const bfrag*)(Vbuf[d] + (row) * 128 + (((ch) ^ ((row) & 7)) << 4)))

#pragma unroll 1
  for (int half = 0; half < 2; ++half) {
    const int qt = half ? (31 - p) : p;
    const int nkv = qt + 1;
    const int lo = (z * nkv) / 3, hi = ((z + 1) * nkv) / 3;
    const int nj = hi - lo;
    const int qr = qt * 64 + wid * 16;
    const bf16_t* Qb = qh + ((size_t)h * 2048 + qr) * 128;
    bfrag qf[4];
#pragma unroll
    for (int ks = 0; ks < 4; ++ks)
      qf[ks] = *(const bfrag*)&Qb[lc * 128 + ks * 32 + lg * 8];
    f32x4 O[8] = {};
    float mr[4] = {-1e30f, -1e30f, -1e30f, -1e30f};
    float lsum[4] = {0.f, 0.f, 0.f, 0.f};

    if (nj > 0) {
      stage(lo * 64, 0);
      asm volatile("s_waitcnt vmcnt(0)" ::: "memory");
      __builtin_amdgcn_s_barrier();
    }
#pragma unroll 1
    for (int j = 0; j < nj; ++j) {
      const int kt = lo + j, d = j & 1;
      const int kv0 = kt * 64;
      if (j + 1 < nj) stage(kv0 + 64, d ^ 1);  // overlap with compute
      f32x4 s[4];
#pragma unroll
      for (int c = 0; c < 4; ++c) {
        f32x4 a = {};
#pragma unroll
        for (int ks = 0; ks < 4; ++ks) {
          bfrag kf = FRK(d, c * 16 + lc, ks * 4 + lg);
          a = MFMA16(qf[ks], kf, a);
        }
        s[c] = a;
      }
      if (kt == qt) {  // diagonal tile: causal mask
#pragma unroll
        for (int c = 0; c < 4; ++c)
#pragma unroll
          for (int i = 0; i < 4; ++i)
            if (kv0 + c * 16 + lc > qr + lg * 4 + i) s[c][i] = -1e10f;
      }
      float pm[4];
#pragma unroll
      for (int i = 0; i < 4; ++i)
        pm[i] = fmaxf(fmaxf(s[0][i], s[1][i]), fmaxf(s[2][i], s[3][i]));
#pragma unroll
      for (int m = 1; m < 16; m <<= 1)
#pragma unroll
        for (int i = 0; i < 4; ++i) pm[i] = fmaxf(pm[i], __shfl_xor(pm[i], m));
      // T13 defer-max: skip O-rescale when max growth <= 8 for all rows (wave-uniform)
      bool small = true;
#pragma unroll
      for (int i = 0; i < 4; ++i) small = small && (pm[i] <= mr[i] + 8.f);
      const bool skip = __all(small);
      float al[4], rs[4];
#pragma unroll
      for (int i = 0; i < 4; ++i) {
        const float mn = skip ? mr[i] : fmaxf(mr[i], pm[i]);
        al[i] = __expf(mr[i] - mn);
        mr[i] = mn;
        rs[i] = 0.f;
      }
#pragma unroll
      for (int c = 0; c < 4; ++c)
#pragma unroll
        for (int i = 0; i < 4; ++i) {
          const float pv = __expf(s[c][i] - mr[i]);
          s[c][i] = pv; rs[i] += pv;
        }
#pragma unroll
      for (int m = 1; m < 16; m <<= 1)
#pragma unroll
        for (int i = 0; i < 4; ++i) rs[i] += __shfl_xor(rs[i], m);
#pragma unroll
      for (int i = 0; i < 4; ++i) lsum[i] = lsum[i] * al[i] + rs[i];
      if (!skip) {
#pragma unroll
        for (int n = 0; n < 8; ++n)
#pragma unroll
          for (int i = 0; i < 4; ++i) O[n][i] *= al[i];
      }
#pragma unroll
      for (int c = 0; c < 4; ++c)
#pragma unroll
        for (int i = 0; i < 4; ++i)
          Ps[wid][(lg * 4 + i) * 72 + c * 16 + lc] = bf16_t(s[c][i]);
#pragma unroll
      for (int k2 = 0; k2 < 2; ++k2) {
        bfrag pf = *(const bfrag*)((const char*)&Ps[wid][0] + lc * 144 + k2 * 64 + lg * 16);
#pragma unroll
        for (int n = 0; n < 8; ++n) {
          bfrag vf = FRV(d, n * 16 + lc, k2 * 4 + lg);
          O[n] = MFMA16(pf, vf, O[n]);
        }
      }
      if (j + 1 < nj) asm volatile("s_waitcnt vmcnt(0)" ::: "memory");
      asm volatile("s_waitcnt lgkmcnt(0)" ::: "memory");
      __builtin_amdgcn_s_barrier();
    }
    const size_t rb = (size_t)(z * 16 + h) * 2048 + qr;
#pragma unroll
    for (int n = 0; n < 8; ++n)
#pragma unroll
      for (int i = 0; i < 4; ++i)
        Op[(rb + lg * 4 + i) * 128 + n * 16 + lc] = bf16_t(O[n][i]);
    if (lc == 0) {
#pragma unroll
      for (int i = 0; i < 4; ++i)
        ml[rb + lg * 4 + i] = make_float2(mr[i], lsum[i]);
    }
    __builtin_amdgcn_s_barrier();
  }
#undef FRK
#undef FRV
}

// ---------- combine z=3 attention partials -> av bf16 [2048][2048] ----------
__global__ __launch_bounds__(256) void attn_combine(const bf16_t* __restrict__ Op,
    const float2* __restrict__ ml, bf16_t* __restrict__ av) {
  const int idx = blockIdx.x * 256 + threadIdx.x;
  const int t = idx & 15, hr = idx >> 4;
  const int ZS = 16 * 2048;
  const size_t ZO = (size_t)ZS * 128;
  const float2 m0 = ml[hr], m1 = ml[ZS + hr], m2 = ml[2 * ZS + hr];
  const float M = fmaxf(fmaxf(m0.x, m1.x), m2.x);
  const float w0 = __expf(m0.x - M), w1 = __expf(m1.x - M), w2 = __expf(m2.x - M);
  const float inv = 1.f / (w0 * m0.y + w1 * m1.y + w2 * m2.y);
  const bf16_t* p0 = Op + (size_t)hr * 128 + t * 8;
  uint4 a0 = *(const uint4*)p0;
  uint4 a1 = *(const uint4*)(p0 + ZO);
  uint4 a2 = *(const uint4*)(p0 + 2 * ZO);
  const unsigned* u0 = (const unsigned*)&a0;
  const unsigned* u1 = (const unsigned*)&a1;
  const unsigned* u2 = (const unsigned*)&a2;
  bf16_t ov[8];
#pragma unroll
  for (int j = 0; j < 8; ++j) {
    const int w = j >> 1, sh = (j & 1) * 16;
    ov[j] = bf16_t((w0 * bf2f((u0[w] >> sh) & 0xffffu) +
                    w1 * bf2f((u1[w] >> sh) & 0xffffu) +
                    w2 * bf2f((u2[w] >> sh) & 0xffffu)) * inv);
  }
  const int row = hr & 2047, hh = hr >> 11;
  *(uint4*)(av + (size_t)row * 2048 + hh * 128 + t * 8) = *(const uint4*)ov;
}

extern "C" void kernel_launch(void* const* d_in, const int* in_sizes, int n_in,
                              void* d_out, int out_size, void* d_ws, size_t ws_size,
                              hipStream_t stream) {
  const float* x        = (const float*)d_in[0];
  const float* ln_scale = (const float*)d_in[1];
  const float* ln_offset= (const float*)d_in[2];
  const float* w_qkv    = (const float*)d_in[3];   // [2048][6144]
  const float* w_ao     = (const float*)d_in[4];   // [2048][2048]
  const float* w_ff_in  = (const float*)d_in[5];   // [2048][8192]
  const float* b_ff_in  = (const float*)d_in[6];   // [8192]
  const float* w_ff_out = (const float*)d_in[7];   // [8192][2048]
  const float* b_ff_out = (const float*)d_in[8];   // [2048]
  float* out = (float*)d_out;

  char* ws = (char*)d_ws;
  bf16_t* wqkvT   = (bf16_t*)(ws);                  // [6144][2048]; dead after qkv GEMM
  bf16_t* waoT    = (bf16_t*)(ws + 25165824);       // [2048][2048]
  bf16_t* wffinT  = (bf16_t*)(ws + 33554432);       // [8192][2048]
  bf16_t* wffoutT = (bf16_t*)(ws + 67108864);       // [2048][8192]
  bf16_t* h       = (bf16_t*)(ws + 100663296);      // [2048][2048]
  bf16_t* qhb     = (bf16_t*)(ws + 109051904);      // [16][2048][128]
  bf16_t* khb     = (bf16_t*)(ws + 117440512);
  bf16_t* vTb     = (bf16_t*)(ws + 125829120);      // [16][128][2048]
  bf16_t* avb     = (bf16_t*)(ws + 134217728);      // [2048][2048]
  bf16_t* qkvb    = (bf16_t*)(ws + 142606336);      // [2048][6144]; later pab / ff1
  bf16_t* ff1b    = qkvb;
  bf16_t* pab     = qkvb;                           // attn_out bf16 partials 4x[2048][2048]
  float*  pf      = (float*)(ws);                   // ff_out f32 partials (dead weights)
  bf16_t* Opart   = (bf16_t*)(ws);                  // attn partials 3x[16][2048][128] bf16
  float2* mlpart  = (float2*)(ws + 167772160);      // 3x[16][2048] float2

  hipFuncSetAttribute((const void*)gemm8p<0>,  hipFuncAttributeMaxDynamicSharedMemorySize, 131072);
  hipFuncSetAttribute((const void*)gemm8p<8>,  hipFuncAttributeMaxDynamicSharedMemorySize, 131072);
  hipFuncSetAttribute((const void*)gemm8p<11>, hipFuncAttributeMaxDynamicSharedMemorySize, 131072);

  dim3 b256(256), b512(512);
  transpose_cvt4<<<dim3(12288), b256, 0, stream>>>(w_qkv, wqkvT, w_ao, waoT,
                                                   w_ff_in, wffinT, w_ff_out, wffoutT);
  ln_kernel<<<dim3(2048), b256, 0, stream>>>(x, ln_scale, ln_offset, h);

  gemm8p<8><<<dim3(24, 8, 1), b512, 131072, stream>>>(h, 2048, wqkvT, 2048,
      nullptr, nullptr, qkvb, 2048, 6144, 2048, 0);
  rope_kernel<<<dim3(2048, 16), dim3(128), 0, stream>>>(qkvb, qhb, khb, vTb);

  attn_kernel<<<dim3(16, 16, 3), b256, 0, stream>>>(qhb, khb, vTb, Opart, mlpart);
  attn_combine<<<dim3(2048), b256, 0, stream>>>(Opart, mlpart, avb);

  // attn_out: split-K=4 (K=512 each), bf16 partials in dead qkvb region
  gemm8p<8><<<dim3(8, 8, 4), b512, 131072, stream>>>(avb, 2048, waoT, 2048,
      nullptr, nullptr, pab, 2048, 2048, 512, (size_t)2048 * 2048);
  reduce4b<<<dim3(2048), b256, 0, stream>>>(pab, pab + 4194304, pab + 2 * 4194304,
      pab + 3 * 4194304, out, 4194304);

  gemm8p<11><<<dim3(32, 8, 1), b512, 131072, stream>>>(h, 2048, wffinT, 2048,
      b_ff_in, nullptr, ff1b, 2048, 8192, 2048, 0);

  // ff_out: split-K=4 (K=2048 each), f32 partials over dead weight region
  gemm8p<0><<<dim3(8, 8, 4), b512, 131072, stream>>>(ff1b, 8192, wffoutT, 8192,
      nullptr, pf, nullptr, 2048, 2048, 2048, (size_t)2048 * 2048);
  reduceP<4, true, true><<<dim3(4096), b256, 0, stream>>>(pf, pf + 4194304,
      pf + 2 * 4194304, pf + 3 * 4194304, b_ff_out, out, 4194304, 2047);
}

// Round 11
// 393.420 us; speedup vs baseline: 2.3352x; 1.0485x over previous
//
#include <hip/hip_runtime.h>
#include <hip/hip_bf16.h>

using bf16_t = __hip_bfloat16;
typedef __attribute__((ext_vector_type(8))) __bf16 bfrag;   // 8 bf16 = 4 VGPR (MFMA A/B operand)
typedef __attribute__((ext_vector_type(4))) float f32x4;    // MFMA C/D operand

#define MFMA16(a, b, c) __builtin_amdgcn_mfma_f32_16x16x32_bf16((a), (b), (c), 0, 0, 0)

__device__ __forceinline__ void gload_lds16(const void* g, void* l) {
  // async global->LDS, 16B/lane; LDS dest = wave-uniform base + lane*16
  __builtin_amdgcn_global_load_lds((const __attribute__((address_space(1))) void*)g,
                                   (__attribute__((address_space(3))) void*)l, 16, 0, 0);
}

__device__ __forceinline__ float bf2f(unsigned u) { return __uint_as_float(u << 16); }

// ---------- fused: 4x weight transpose/convert + LayerNorm, one launch ----------
// transpose: in[K][N] f32 -> out[N][K] bf16, 64x64 tiles (blocks 0..12287)
// layernorm: blocks 12288..14335, one row each
__global__ __launch_bounds__(256) void prep_kernel(
    const float* __restrict__ in0, bf16_t* __restrict__ out0,
    const float* __restrict__ in1, bf16_t* __restrict__ out1,
    const float* __restrict__ in2, bf16_t* __restrict__ out2,
    const float* __restrict__ in3, bf16_t* __restrict__ out3,
    const float* __restrict__ x, const float* __restrict__ sc,
    const float* __restrict__ of, bf16_t* __restrict__ hh) {
  int b = blockIdx.x;
  if (b >= 12288) {  // ---- LayerNorm row
    __shared__ float red[8];
    const int n = b - 12288, tid = threadIdx.x;
    const float* xr = x + (size_t)n * 2048;
    float4 a = ((const float4*)xr)[tid * 2];
    float4 bb = ((const float4*)xr)[tid * 2 + 1];
    float s = a.x + a.y + a.z + a.w + bb.x + bb.y + bb.z + bb.w;
    float q = a.x * a.x + a.y * a.y + a.z * a.z + a.w * a.w +
              bb.x * bb.x + bb.y * bb.y + bb.z * bb.z + bb.w * bb.w;
#pragma unroll
    for (int m = 32; m; m >>= 1) { s += __shfl_xor(s, m); q += __shfl_xor(q, m); }
    if ((tid & 63) == 0) { red[(tid >> 6) * 2] = s; red[(tid >> 6) * 2 + 1] = q; }
    __syncthreads();
    s = red[0] + red[2] + red[4] + red[6];
    q = red[1] + red[3] + red[5] + red[7];
    const float mu = s * (1.f / 2048.f);
    const float inv = rsqrtf(q * (1.f / 2048.f) - mu * mu + 1e-5f);
    const int base = tid * 8;
    float v[8] = {a.x, a.y, a.z, a.w, bb.x, bb.y, bb.z, bb.w};
    bf16_t* hr = hh + (size_t)n * 2048 + base;
#pragma unroll
    for (int j = 0; j < 8; ++j) hr[j] = bf16_t((v[j] - mu) * inv * sc[base + j] + of[base + j]);
    return;
  }
  __shared__ float t[64][65];
  const float* in; bf16_t* out; int K, N, nx;
  if (b < 3072)      { in = in0; out = out0; K = 2048; N = 6144; nx = 96; }
  else if (b < 4096) { in = in1; out = out1; K = 2048; N = 2048; nx = 32; b -= 3072; }
  else if (b < 8192) { in = in2; out = out2; K = 2048; N = 8192; nx = 128; b -= 4096; }
  else               { in = in3; out = out3; K = 8192; N = 2048; nx = 32; b -= 8192; }
  const int n0 = (b % nx) * 64, k0 = (b / nx) * 64;
  const int tx = threadIdx.x & 15, ty = threadIdx.x >> 4;   // 16 x 16
#pragma unroll
  for (int i = 0; i < 4; ++i) {
    float4 v = *(const float4*)&in[(size_t)(k0 + i * 16 + ty) * N + n0 + tx * 4];
    t[i * 16 + ty][tx * 4 + 0] = v.x; t[i * 16 + ty][tx * 4 + 1] = v.y;
    t[i * 16 + ty][tx * 4 + 2] = v.z; t[i * 16 + ty][tx * 4 + 3] = v.w;
  }
  __syncthreads();
#pragma unroll
  for (int i = 0; i < 4; ++i) {
    const int n = i * 16 + ty;
    bf16_t w[4];
#pragma unroll
    for (int j = 0; j < 4; ++j) w[j] = bf16_t(t[tx * 4 + j][n]);
    *(uint2*)&out[(size_t)(n0 + n) * K + k0 + tx * 4] = *(const uint2*)w;
  }
}

// ---------- m201-style 8-phase 256x256 GEMM (R8-proven): C = A*BT^T ----------
// 8 phases / 2 K-tiles; reads 12/4/8/0 per phase; vmcnt(4) at ph4/ph8 only.
// EPI bits: 1=+bias, 2=gelu, 8=store bf16 (else f32)
template <int EPI>
__global__ __launch_bounds__(512, 2) void gemm8p(
    const bf16_t* __restrict__ A, int lda, const bf16_t* __restrict__ BT, int ldb,
    const float* __restrict__ bias, float* __restrict__ Cf, bf16_t* __restrict__ Cb,
    int M, int N, int K, size_t splitStride) {
  extern __shared__ __align__(16) char lds[];   // 128 KiB
  const int tid = threadIdx.x, wid = tid >> 6, lane = tid & 63;
  const int lc = lane & 15, lg = lane >> 4;
  const int bm = blockIdx.y * 256, bn = blockIdx.x * 256;
  const int wr = wid >> 2, wc = wid & 3;              // 2M x 4N waves, each 128x64 out
  const int NT = K >> 6, niter = NT >> 1;             // NT even
  const int srow = tid >> 3;
  const int scol = (((tid & 7) ^ ((tid >> 3) & 7)) << 3);
  const bf16_t* Abase = A + (size_t)blockIdx.z * K + (size_t)(bm + srow) * lda + scol;
  const bf16_t* Bbase = BT + (size_t)blockIdx.z * K + (size_t)(bn + srow) * ldb + scol;
  auto SA = [&](int T, int h) {
    char* dst = lds + (T & 1) * 32768 + h * 16384 + wid * 1024;
    const bf16_t* src = Abase + (size_t)(h * 128) * lda + T * 64;
    gload_lds16(src, dst); gload_lds16(src + (size_t)64 * lda, dst + 8192);
  };
  auto SB = [&](int T, int h) {
    char* dst = lds + 65536 + (T & 1) * 32768 + h * 16384 + wid * 1024;
    const bf16_t* src = Bbase + (size_t)(h * 128) * ldb + T * 64;
    gload_lds16(src, dst); gload_lds16(src + (size_t)64 * ldb, dst + 8192);
  };
#define FRA(d, row, kk) (*(const bfrag*)(lds + (d) * 32768 + wr * 16384 + (row) * 128 + \
    ((((kk) * 4 + lg) ^ ((row) & 7)) << 4)))
#define FRB(d, row, kk) (*(const bfrag*)(lds + 65536 + (d) * 32768 + (wc >> 1) * 16384 + \
    (row) * 128 + ((((kk) * 4 + lg) ^ ((row) & 7)) << 4)))
#define PHASE_SYNC() do { __builtin_amdgcn_s_barrier(); \
    asm volatile("s_waitcnt lgkmcnt(0)" ::: "memory"); \
    __builtin_amdgcn_sched_barrier(0); __builtin_amdgcn_s_setprio(1); } while (0)
#define PHASE_END() do { __builtin_amdgcn_s_setprio(0); __builtin_amdgcn_s_barrier(); } while (0)
#define PHASE_END_VM(lastf) do { __builtin_amdgcn_s_setprio(0); \
    if (lastf) asm volatile("s_waitcnt vmcnt(0)" ::: "memory"); \
    else       asm volatile("s_waitcnt vmcnt(4)" ::: "memory"); \
    __builtin_amdgcn_s_barrier(); } while (0)

  // prologue: tile0 all 4 halves + tile1 B halves
  SB(0, 0); SB(0, 1); SA(0, 0); SA(0, 1); SB(1, 0); SB(1, 1);
  asm volatile("s_waitcnt vmcnt(4)" ::: "memory");    // tile0 landed
  __builtin_amdgcn_s_barrier();

  f32x4 acc[8][4] = {};
  const int brl = (wc & 1) * 64 + lc;                 // B local row base (+n*16)

  for (int k = 0; k < niter; ++k) {
    const int T1 = 2 * k + 1, T2 = 2 * k + 2, T3 = 2 * k + 3;
    const bool last = (k == niter - 1);
    bfrag aq[4][2], b01[2][2], b23[2][2];
#pragma unroll 1
    for (int d = 0; d < 2; ++d) {                     // d=0: phases 1-4, d=1: phases 5-8
      // ---- phase 1/5: read a0-quad + b01; stage SA(T1,0) / SA(T2,0)
#pragma unroll
      for (int m = 0; m < 4; ++m)
#pragma unroll
        for (int kk = 0; kk < 2; ++kk) aq[m][kk] = FRA(d, m * 16 + lc, kk);
#pragma unroll
      for (int n = 0; n < 2; ++n)
#pragma unroll
        for (int kk = 0; kk < 2; ++kk) b01[n][kk] = FRB(d, brl + n * 16, kk);
      if (d == 0) SA(T1, 0); else if (!last) SA(T2, 0);
      PHASE_SYNC();
#pragma unroll
      for (int kk = 0; kk < 2; ++kk)
#pragma unroll
        for (int m = 0; m < 4; ++m) {
          acc[m][0] = MFMA16(aq[m][kk], b01[0][kk], acc[m][0]);
          acc[m][1] = MFMA16(aq[m][kk], b01[1][kk], acc[m][1]);
        }
      PHASE_END();
      // ---- phase 2/6: read b23; stage SA(T1,1) / SA(T2,1)
#pragma unroll
      for (int n = 0; n < 2; ++n)
#pragma unroll
        for (int kk = 0; kk < 2; ++kk) b23[n][kk] = FRB(d, brl + (n + 2) * 16, kk);
      if (d == 0) SA(T1, 1); else if (!last) SA(T2, 1);
      PHASE_SYNC();
#pragma unroll
      for (int kk = 0; kk < 2; ++kk)
#pragma unroll
        for (int m = 0; m < 4; ++m) {
          acc[m][2] = MFMA16(aq[m][kk], b23[0][kk], acc[m][2]);
          acc[m][3] = MFMA16(aq[m][kk], b23[1][kk], acc[m][3]);
        }
      PHASE_END();
      // ---- phase 3/7: read a1-quad; stage SB(T2,0) / SB(T3,0)
#pragma unroll
      for (int m = 0; m < 4; ++m)
#pragma unroll
        for (int kk = 0; kk < 2; ++kk) aq[m][kk] = FRA(d, (m + 4) * 16 + lc, kk);
      if (!last) { if (d == 0) SB(T2, 0); else SB(T3, 0); }
      PHASE_SYNC();
#pragma unroll
      for (int kk = 0; kk < 2; ++kk)
#pragma unroll
        for (int m = 0; m < 4; ++m) {
          acc[4 + m][2] = MFMA16(aq[m][kk], b23[0][kk], acc[4 + m][2]);
          acc[4 + m][3] = MFMA16(aq[m][kk], b23[1][kk], acc[4 + m][3]);
        }
      PHASE_END();
      // ---- phase 4/8: no reads; stage SB(T2,1) / SB(T3,1); counted vmcnt
      if (!last) { if (d == 0) SB(T2, 1); else SB(T3, 1); }
      PHASE_SYNC();
#pragma unroll
      for (int kk = 0; kk < 2; ++kk)
#pragma unroll
        for (int m = 0; m < 4; ++m) {
          acc[4 + m][0] = MFMA16(aq[m][kk], b01[0][kk], acc[4 + m][0]);
          acc[4 + m][1] = MFMA16(aq[m][kk], b01[1][kk], acc[4 + m][1]);
        }
      PHASE_END_VM(last);
    }
  }
#undef FRA
#undef FRB
#undef PHASE_SYNC
#undef PHASE_END
#undef PHASE_END_VM
  // ---- epilogue: per-wave LDS staging -> coalesced vector stores
  char* W = lds + wid * 16384;
  if (EPI & 8) {
    bf16_t* Wb = (bf16_t*)W;
    bf16_t* Cbz = Cb + (size_t)blockIdx.z * splitStride;
#pragma unroll
    for (int mc = 0; mc < 2; ++mc) {
#pragma unroll
      for (int m4 = 0; m4 < 4; ++m4) {
#pragma unroll
        for (int n = 0; n < 4; ++n) {
          const int col = bn + wc * 64 + n * 16 + lc;
          float bv = (EPI & 1) ? bias[col] : 0.f;
#pragma unroll
          for (int i = 0; i < 4; ++i) {
            float v = acc[mc * 4 + m4][n][i];
            if (EPI & 1) v += bv;
            if (EPI & 2) v = 0.5f * v * (1.f + tanhf(0.7978845608028654f * (v + 0.044715f * v * v * v)));
            Wb[(m4 * 16 + lg * 4 + i) * 72 + n * 16 + lc] = bf16_t(v);
          }
        }
      }
      asm volatile("s_waitcnt lgkmcnt(0)" ::: "memory");
      __builtin_amdgcn_sched_barrier(0);
#pragma unroll
      for (int p = 0; p < 8; ++p) {
        const int rl = p * 8 + (lane >> 3), j = lane & 7;
        uint4 v = *(const uint4*)&Wb[rl * 72 + j * 8];
        const int grow = bm + wr * 128 + mc * 64 + rl;
        const int gcol = bn + wc * 64 + j * 8;
        *(uint4*)&Cbz[(size_t)grow * N + gcol] = v;
      }
      asm volatile("s_waitcnt lgkmcnt(0)" ::: "memory");
      __builtin_amdgcn_sched_barrier(0);
    }
  } else {
    float* Wf = (float*)W;
    float* Cfz = Cf + (size_t)blockIdx.z * splitStride;
#pragma unroll
    for (int mc = 0; mc < 4; ++mc) {
#pragma unroll
      for (int m2 = 0; m2 < 2; ++m2) {
#pragma unroll
        for (int n = 0; n < 4; ++n) {
          const int col = bn + wc * 64 + n * 16 + lc;
          float bv = (EPI & 1) ? bias[col] : 0.f;
#pragma unroll
          for (int i = 0; i < 4; ++i) {
            float v = acc[mc * 2 + m2][n][i];
            if (EPI & 1) v += bv;
            if (EPI & 2) v = 0.5f * v * (1.f + tanhf(0.7978845608028654f * (v + 0.044715f * v * v * v)));
            Wf[(m2 * 16 + lg * 4 + i) * 72 + n * 16 + lc] = v;
          }
        }
      }
      asm volatile("s_waitcnt lgkmcnt(0)" ::: "memory");
      __builtin_amdgcn_sched_barrier(0);
#pragma unroll
      for (int p = 0; p < 8; ++p) {
        const int rl = p * 4 + (lane >> 4), j = lane & 15;
        float4 v = *(const float4*)&Wf[rl * 72 + j * 4];
        const int grow = bm + wr * 128 + mc * 32 + rl;
        const int gcol = bn + wc * 64 + j * 4;
        *(float4*)&Cfz[(size_t)grow * N + gcol] = v;
      }
      asm volatile("s_waitcnt lgkmcnt(0)" ::: "memory");
      __builtin_amdgcn_sched_barrier(0);
    }
  }
}

// ---------- final reduce: out = sum4(pa bf16) + sum4(pfb bf16) + b_ff_out[col] ----------
__global__ __launch_bounds__(256) void reduce_final(const bf16_t* __restrict__ pa,
    const bf16_t* __restrict__ pfb, const float* __restrict__ bias,
    float* __restrict__ out, int total) {
  const int i = (blockIdx.x * 256 + threadIdx.x) * 8;
  if (i >= total) return;
  const size_t S = 4194304;
  float r[8] = {};
#pragma unroll
  for (int z = 0; z < 4; ++z) {
    uint4 a = *(const uint4*)(pa + z * S + i);
    uint4 b = *(const uint4*)(pfb + z * S + i);
    const unsigned* ua = (const unsigned*)&a;
    const unsigned* ub = (const unsigned*)&b;
#pragma unroll
    for (int j = 0; j < 8; ++j) {
      const int w = j >> 1, sh = (j & 1) * 16;
      r[j] += bf2f((ua[w] >> sh) & 0xffffu) + bf2f((ub[w] >> sh) & 0xffffu);
    }
  }
  const int cb = i & 2047;
  float4 b0 = *(const float4*)(bias + cb);
  float4 b1 = *(const float4*)(bias + cb + 4);
  r[0] += b0.x; r[1] += b0.y; r[2] += b0.z; r[3] += b0.w;
  r[4] += b1.x; r[5] += b1.y; r[6] += b1.z; r[7] += b1.w;
  *(float4*)(out + i) = make_float4(r[0], r[1], r[2], r[3]);
  *(float4*)(out + i + 4) = make_float4(r[4], r[5], r[6], r[7]);
}

// ---------- RoPE + head split ----------
__global__ __launch_bounds__(128) void rope_kernel(const bf16_t* __restrict__ qkv,
    bf16_t* __restrict__ qh, bf16_t* __restrict__ kh, bf16_t* __restrict__ vT) {
  const int n = blockIdx.x, hh = blockIdx.y;
  const int d = threadIdx.x;
  const int mp = hh >> 2, hi = hh & 3;
  const bf16_t* row = qkv + (size_t)n * 6144 + mp * 1536 + hi * 128;  // [q|v|k] each 512 per mp
  float q = __bfloat162float(row[d]);
  float k = __bfloat162float(row[1024 + d]);
  if (d < 64) {  // wave-uniform branch
    const float ang = (float)n * powf(10000.f, -(float)(d & ~1) / 64.f);
    const float sn = sinf(ang), cs = cosf(ang);
    const float qp = __shfl_xor(q, 1), kp = __shfl_xor(k, 1);
    if (d & 1) { q = q * cs + qp * sn; k = k * cs + kp * sn; }
    else       { q = q * cs - qp * sn; k = k * cs - kp * sn; }
  }
  qh[((size_t)hh * 2048 + n) * 128 + d] = bf16_t(q * 0.08838834764831845f); // 1/sqrt(128)
  kh[((size_t)hh * 2048 + n) * 128 + d] = bf16_t(k);
  vT[((size_t)hh * 128 + d) * 2048 + n] = row[512 + d];
}

// ---------- causal flash attention, pairs + KV-split(z=3), partial (O,m,l) output ----------
__global__ __launch_bounds__(256) void attn_kernel(const bf16_t* __restrict__ qh,
    const bf16_t* __restrict__ kh, const bf16_t* __restrict__ vT,
    bf16_t* __restrict__ Op, float2* __restrict__ ml) {
  __shared__ alignas(16) char Kbuf[2][16384];    // [kv 64][d 128] bf16, chunk ^= row&15
  __shared__ alignas(16) char Vbuf[2][16384];    // [d 128][kv 64] bf16, chunk ^= row&7
  __shared__ alignas(16) bf16_t Ps[4][16 * 72];  // per-wave P, stride 72
  const int p = blockIdx.x, h = blockIdx.y, z = blockIdx.z;
  const int tid = threadIdx.x, wid = tid >> 6, lane = tid & 63;
  const int lc = lane & 15, lg = lane >> 4;
  const int krow = wid * 4 + (lane >> 4);
  const int vrow = wid * 8 + (lane >> 3);

  auto stage = [&](int kv0, int d) {
#pragma unroll
    for (int i = 0; i < 4; ++i) {
      const int kr = i * 16 + krow;
      const int kch = (lane & 15) ^ (kr & 15);
      gload_lds16(kh + ((size_t)h * 2048 + kv0 + kr) * 128 + kch * 8,
                  Kbuf[d] + i * 4096 + wid * 1024);
      const int vr = i * 32 + vrow;
      const int vch = (lane & 7) ^ (vr & 7);
      gload_lds16(vT + ((size_t)h * 128 + vr) * 2048 + kv0 + vch * 8,
                  Vbuf[d] + i * 4096 + wid * 1024);
    }
  };
#define FRK(d, row, ch) (*(const bfrag*)(Kbuf[d] + (row) * 256 + (((ch) ^ ((row) & 15)) << 4)))
#define FRV(d, row, ch) (*(const bfrag*)(Vbuf[d] + (row) * 128 + (((ch) ^ ((row) & 7)) << 4)))

#pragma unroll 1
  for (int half = 0; half < 2; ++half) {
    const int qt = half ? (31 - p) : p;
    const int nkv = qt + 1;
    const int lo = (z * nkv) / 3, hi = ((z + 1) * nkv) / 3;
    const int nj = hi - lo;
    const int qr = qt * 64 + wid * 16;
    const bf16_t* Qb = qh + ((size_t)h * 2048 + qr) * 128;
    bfrag qf[4];
#pragma unroll
    for (int ks = 0; ks < 4; ++ks)
      qf[ks] = *(const bfrag*)&Qb[lc * 128 + ks * 32 + lg * 8];
    f32x4 O[8] = {};
    float mr[4] = {-1e30f, -1e30f, -1e30f, -1e30f};
    float lsum[4] = {0.f, 0.f, 0.f, 0.f};

    if (nj > 0) {
      stage(lo * 64, 0);
      asm volatile("s_waitcnt vmcnt(0)" ::: "memory");
      __builtin_amdgcn_s_barrier();
    }
#pragma unroll 1
    for (int j = 0; j < nj; ++j) {
      const int kt = lo + j, d = j & 1;
      const int kv0 = kt * 64;
      if (j + 1 < nj) stage(kv0 + 64, d ^ 1);  // overlap with compute
      f32x4 s[4];
#pragma unroll
      for (int c = 0; c < 4; ++c) {
        f32x4 a = {};
#pragma unroll
        for (int ks = 0; ks < 4; ++ks) {
          bfrag kf = FRK(d, c * 16 + lc, ks * 4 + lg);
          a = MFMA16(qf[ks], kf, a);
        }
        s[c] = a;
      }
      if (kt == qt) {  // diagonal tile: causal mask
#pragma unroll
        for (int c = 0; c < 4; ++c)
#pragma unroll
          for (int i = 0; i < 4; ++i)
            if (kv0 + c * 16 + lc > qr + lg * 4 + i) s[c][i] = -1e10f;
      }
      float pm[4];
#pragma unroll
      for (int i = 0; i < 4; ++i)
        pm[i] = fmaxf(fmaxf(s[0][i], s[1][i]), fmaxf(s[2][i], s[3][i]));
#pragma unroll
      for (int m = 1; m < 16; m <<= 1)
#pragma unroll
        for (int i = 0; i < 4; ++i) pm[i] = fmaxf(pm[i], __shfl_xor(pm[i], m));
      // T13 defer-max: skip O-rescale when max growth <= 8 for all rows (wave-uniform)
      bool small = true;
#pragma unroll
      for (int i = 0; i < 4; ++i) small = small && (pm[i] <= mr[i] + 8.f);
      const bool skip = __all(small);
      float al[4], rs[4];
#pragma unroll
      for (int i = 0; i < 4; ++i) {
        const float mn = skip ? mr[i] : fmaxf(mr[i], pm[i]);
        al[i] = __expf(mr[i] - mn);
        mr[i] = mn;
        rs[i] = 0.f;
      }
#pragma unroll
      for (int c = 0; c < 4; ++c)
#pragma unroll
        for (int i = 0; i < 4; ++i) {
          const float pv = __expf(s[c][i] - mr[i]);
          s[c][i] = pv; rs[i] += pv;
        }
#pragma unroll
      for (int m = 1; m < 16; m <<= 1)
#pragma unroll
        for (int i = 0; i < 4; ++i) rs[i] += __shfl_xor(rs[i], m);
#pragma unroll
      for (int i = 0; i < 4; ++i) lsum[i] = lsum[i] * al[i] + rs[i];
      if (!skip) {
#pragma unroll
        for (int n = 0; n < 8; ++n)
#pragma unroll
          for (int i = 0; i < 4; ++i) O[n][i] *= al[i];
      }
#pragma unroll
      for (int c = 0; c < 4; ++c)
#pragma unroll
        for (int i = 0; i < 4; ++i)
          Ps[wid][(lg * 4 + i) * 72 + c * 16 + lc] = bf16_t(s[c][i]);
#pragma unroll
      for (int k2 = 0; k2 < 2; ++k2) {
        bfrag pf = *(const bfrag*)((const char*)&Ps[wid][0] + lc * 144 + k2 * 64 + lg * 16);
#pragma unroll
        for (int n = 0; n < 8; ++n) {
          bfrag vf = FRV(d, n * 16 + lc, k2 * 4 + lg);
          O[n] = MFMA16(pf, vf, O[n]);
        }
      }
      if (j + 1 < nj) asm volatile("s_waitcnt vmcnt(0)" ::: "memory");
      asm volatile("s_waitcnt lgkmcnt(0)" ::: "memory");
      __builtin_amdgcn_s_barrier();
    }
    const size_t rb = (size_t)(z * 16 + h) * 2048 + qr;
#pragma unroll
    for (int n = 0; n < 8; ++n)
#pragma unroll
      for (int i = 0; i < 4; ++i)
        Op[(rb + lg * 4 + i) * 128 + n * 16 + lc] = bf16_t(O[n][i]);
    if (lc == 0) {
#pragma unroll
      for (int i = 0; i < 4; ++i)
        ml[rb + lg * 4 + i] = make_float2(mr[i], lsum[i]);
    }
    __builtin_amdgcn_s_barrier();
  }
#undef FRK
#undef FRV
}

// ---------- combine z=3 attention partials -> av bf16 [2048][2048] ----------
__global__ __launch_bounds__(256) void attn_combine(const bf16_t* __restrict__ Op,
    const float2* __restrict__ ml, bf16_t* __restrict__ av) {
  const int idx = blockIdx.x * 256 + threadIdx.x;
  const int t = idx & 15, hr = idx >> 4;
  const int ZS = 16 * 2048;
  const size_t ZO = (size_t)ZS * 128;
  const float2 m0 = ml[hr], m1 = ml[ZS + hr], m2 = ml[2 * ZS + hr];
  const float M = fmaxf(fmaxf(m0.x, m1.x), m2.x);
  const float w0 = __expf(m0.x - M), w1 = __expf(m1.x - M), w2 = __expf(m2.x - M);
  const float inv = 1.f / (w0 * m0.y + w1 * m1.y + w2 * m2.y);
  const bf16_t* p0 = Op + (size_t)hr * 128 + t * 8;
  uint4 a0 = *(const uint4*)p0;
  uint4 a1 = *(const uint4*)(p0 + ZO);
  uint4 a2 = *(const uint4*)(p0 + 2 * ZO);
  const unsigned* u0 = (const unsigned*)&a0;
  const unsigned* u1 = (const unsigned*)&a1;
  const unsigned* u2 = (const unsigned*)&a2;
  bf16_t ov[8];
#pragma unroll
  for (int j = 0; j < 8; ++j) {
    const int w = j >> 1, sh = (j & 1) * 16;
    ov[j] = bf16_t((w0 * bf2f((u0[w] >> sh) & 0xffffu) +
                    w1 * bf2f((u1[w] >> sh) & 0xffffu) +
                    w2 * bf2f((u2[w] >> sh) & 0xffffu)) * inv);
  }
  const int row = hr & 2047, hh = hr >> 11;
  *(uint4*)(av + (size_t)row * 2048 + hh * 128 + t * 8) = *(const uint4*)ov;
}

extern "C" void kernel_launch(void* const* d_in, const int* in_sizes, int n_in,
                              void* d_out, int out_size, void* d_ws, size_t ws_size,
                              hipStream_t stream) {
  const float* x        = (const float*)d_in[0];
  const float* ln_scale = (const float*)d_in[1];
  const float* ln_offset= (const float*)d_in[2];
  const float* w_qkv    = (const float*)d_in[3];   // [2048][6144]
  const float* w_ao     = (const float*)d_in[4];   // [2048][2048]
  const float* w_ff_in  = (const float*)d_in[5];   // [2048][8192]
  const float* b_ff_in  = (const float*)d_in[6];   // [8192]
  const float* w_ff_out = (const float*)d_in[7];   // [8192][2048]
  const float* b_ff_out = (const float*)d_in[8];   // [2048]
  float* out = (float*)d_out;

  char* ws = (char*)d_ws;
  // live ranges (proven footprint <= 176.2 MB):
  bf16_t* wqkvT   = (bf16_t*)(ws);                  // 0-25.2    dead after qkv gemm
  bf16_t* waoT    = (bf16_t*)(ws + 25165824);       // 25.2-33.6 dead after attn_out gemm
  bf16_t* wffinT  = (bf16_t*)(ws + 33554432);       // 33.6-67.2 dead after ff_in gemm
  bf16_t* wffoutT = (bf16_t*)(ws + 67108864);       // 67.2-100.7 dead after ff_out gemm
  bf16_t* h       = (bf16_t*)(ws + 100663296);      // 100.7-109.1 dead after ff_in gemm
  bf16_t* qhb     = (bf16_t*)(ws + 109051904);      // [16][2048][128]
  bf16_t* khb     = (bf16_t*)(ws + 117440512);
  bf16_t* vTb     = (bf16_t*)(ws + 125829120);      // [16][128][2048]
  bf16_t* avb     = (bf16_t*)(ws + 134217728);      // [2048][2048]
  bf16_t* qkvb    = (bf16_t*)(ws + 142606336);      // 142.6-167.8 dead after rope
  bf16_t* ff1b    = qkvb;                           // ff1 [2048][8192] 142.6-176.2 (after rope)
  bf16_t* Opart   = (bf16_t*)(ws);                  // attn partials 3x8.4MB over dead wqkvT
  float2* mlpart  = (float2*)(ws + 100663296);      // 786KB over dead h (after ff_in)
  bf16_t* pab     = (bf16_t*)(ws + 33554432);       // attn_out partials 4x8.4MB over dead wffinT
  bf16_t* pfb     = (bf16_t*)(ws);                  // ff_out partials 4x8.4MB over dead wqkvT/waoT

  hipFuncSetAttribute((const void*)gemm8p<8>,  hipFuncAttributeMaxDynamicSharedMemorySize, 131072);
  hipFuncSetAttribute((const void*)gemm8p<11>, hipFuncAttributeMaxDynamicSharedMemorySize, 131072);

  dim3 b256(256), b512(512);
  // weights transpose + LN (independent, one launch)
  prep_kernel<<<dim3(14336), b256, 0, stream>>>(w_qkv, wqkvT, w_ao, waoT,
      w_ff_in, wffinT, w_ff_out, wffoutT, x, ln_scale, ln_offset, h);

  gemm8p<8><<<dim3(24, 8, 1), b512, 131072, stream>>>(h, 2048, wqkvT, 2048,
      nullptr, nullptr, qkvb, 2048, 6144, 2048, 0);
  rope_kernel<<<dim3(2048, 16), dim3(128), 0, stream>>>(qkvb, qhb, khb, vTb);

  // ff_in early (frees wffinT + h for later partials); writes ff1b over dead qkvb
  gemm8p<11><<<dim3(32, 8, 1), b512, 131072, stream>>>(h, 2048, wffinT, 2048,
      b_ff_in, nullptr, ff1b, 2048, 8192, 2048, 0);

  attn_kernel<<<dim3(16, 16, 3), b256, 0, stream>>>(qhb, khb, vTb, Opart, mlpart);
  attn_combine<<<dim3(2048), b256, 0, stream>>>(Opart, mlpart, avb);

  // attn_out: split-K=4 (K=512), bf16 partials over dead wffinT
  gemm8p<8><<<dim3(8, 8, 4), b512, 131072, stream>>>(avb, 2048, waoT, 2048,
      nullptr, nullptr, pab, 2048, 2048, 512, (size_t)2048 * 2048);

  // ff_out: split-K=4 (K=2048), bf16 partials over dead wqkvT/waoT
  gemm8p<8><<<dim3(8, 8, 4), b512, 131072, stream>>>(ff1b, 8192, wffoutT, 8192,
      nullptr, nullptr, pfb, 2048, 2048, 2048, (size_t)2048 * 2048);

  // single fused reduce: out = sum(pab) + sum(pfb) + b_ff_out
  reduce_final<<<dim3(2048), b256, 0, stream>>>(pab, pfb, b_ff_out, out, 4194304);
}

// Round 12
// 391.459 us; speedup vs baseline: 2.3469x; 1.0050x over previous
//
#include <hip/hip_runtime.h>
#include <hip/hip_bf16.h>

using bf16_t = __hip_bfloat16;
typedef __attribute__((ext_vector_type(8))) __bf16 bfrag;   // 8 bf16 = 4 VGPR (MFMA A/B operand)
typedef __attribute__((ext_vector_type(4))) float f32x4;    // MFMA C/D operand

#define MFMA16(a, b, c) __builtin_amdgcn_mfma_f32_16x16x32_bf16((a), (b), (c), 0, 0, 0)

__device__ __forceinline__ void gload_lds16(const void* g, void* l) {
  // async global->LDS, 16B/lane; LDS dest = wave-uniform base + lane*16
  __builtin_amdgcn_global_load_lds((const __attribute__((address_space(1))) void*)g,
                                   (__attribute__((address_space(3))) void*)l, 16, 0, 0);
}

__device__ __forceinline__ float bf2f(unsigned u) { return __uint_as_float(u << 16); }

// ---------- fused prep: 4x weight transpose/convert (2 tiles/block, dbuf) + LayerNorm ----------
// transpose tiles 64x64: in[K][N] f32 -> out[N][K] bf16. blocks 0..6143 = 2 tiles each;
// blocks 6144..8191 = LayerNorm rows.
__global__ __launch_bounds__(256) void prep_kernel(
    const float* __restrict__ in0, bf16_t* __restrict__ out0,
    const float* __restrict__ in1, bf16_t* __restrict__ out1,
    const float* __restrict__ in2, bf16_t* __restrict__ out2,
    const float* __restrict__ in3, bf16_t* __restrict__ out3,
    const float* __restrict__ x, const float* __restrict__ sc,
    const float* __restrict__ of, bf16_t* __restrict__ hh) {
  const int b = blockIdx.x;
  const int tid = threadIdx.x;
  if (b >= 6144) {  // ---- LayerNorm row
    __shared__ float red[8];
    const int n = b - 6144;
    const float* xr = x + (size_t)n * 2048;
    float4 a = ((const float4*)xr)[tid * 2];
    float4 bb = ((const float4*)xr)[tid * 2 + 1];
    float s = a.x + a.y + a.z + a.w + bb.x + bb.y + bb.z + bb.w;
    float q = a.x * a.x + a.y * a.y + a.z * a.z + a.w * a.w +
              bb.x * bb.x + bb.y * bb.y + bb.z * bb.z + bb.w * bb.w;
#pragma unroll
    for (int m = 32; m; m >>= 1) { s += __shfl_xor(s, m); q += __shfl_xor(q, m); }
    if ((tid & 63) == 0) { red[(tid >> 6) * 2] = s; red[(tid >> 6) * 2 + 1] = q; }
    __syncthreads();
    s = red[0] + red[2] + red[4] + red[6];
    q = red[1] + red[3] + red[5] + red[7];
    const float mu = s * (1.f / 2048.f);
    const float inv = rsqrtf(q * (1.f / 2048.f) - mu * mu + 1e-5f);
    const int base = tid * 8;
    float v[8] = {a.x, a.y, a.z, a.w, bb.x, bb.y, bb.z, bb.w};
    bf16_t* hr = hh + (size_t)n * 2048 + base;
#pragma unroll
    for (int j = 0; j < 8; ++j) hr[j] = bf16_t((v[j] - mu) * inv * sc[base + j] + of[base + j]);
    return;
  }
  // ---- two transpose tiles, double-buffered
  __shared__ float t[2][64][65];
  const int tx = tid & 15, ty = tid >> 4;     // 16 x 16 (read phase)
  const float* inb[2]; bf16_t* outb[2]; int Nh[2], Kh[2];
#pragma unroll
  for (int hf = 0; hf < 2; ++hf) {
    int tt = b * 2 + hf;
    const float* in; bf16_t* out; int K, N, nx;
    if (tt < 3072)      { in = in0; out = out0; K = 2048; N = 6144; nx = 96; }
    else if (tt < 4096) { in = in1; out = out1; K = 2048; N = 2048; nx = 32; tt -= 3072; }
    else if (tt < 8192) { in = in2; out = out2; K = 2048; N = 8192; nx = 128; tt -= 4096; }
    else                { in = in3; out = out3; K = 8192; N = 2048; nx = 32; tt -= 8192; }
    const int n0 = (tt % nx) * 64, k0 = (tt / nx) * 64;
    inb[hf] = in + (size_t)k0 * N + n0;
    outb[hf] = out + (size_t)n0 * K + k0;
    Nh[hf] = N; Kh[hf] = K;
  }
  float4 va[2][4];
#pragma unroll
  for (int hf = 0; hf < 2; ++hf)
#pragma unroll
    for (int i = 0; i < 4; ++i)
      va[hf][i] = *(const float4*)(inb[hf] + (size_t)(i * 16 + ty) * Nh[hf] + tx * 4);

#pragma unroll
  for (int hf = 0; hf < 2; ++hf) {
#pragma unroll
    for (int i = 0; i < 4; ++i) {
      t[hf][i * 16 + ty][tx * 4 + 0] = va[hf][i].x;
      t[hf][i * 16 + ty][tx * 4 + 1] = va[hf][i].y;
      t[hf][i * 16 + ty][tx * 4 + 2] = va[hf][i].z;
      t[hf][i * 16 + ty][tx * 4 + 3] = va[hf][i].w;
    }
    __syncthreads();
    // write phase: 8 k-values/thread -> one uint4 per row-visit (16B)
    const int kc = (tid & 7) * 8;
#pragma unroll
    for (int it = 0; it < 2; ++it) {
      const int n = it * 32 + (tid >> 3);
      alignas(16) bf16_t wv[8];
#pragma unroll
      for (int j = 0; j < 8; ++j) wv[j] = bf16_t(t[hf][kc + j][n]);
      *(uint4*)(outb[hf] + (size_t)n * Kh[hf] + kc) = *(const uint4*)wv;
    }
    // no barrier needed between hf=0 stores and hf=1 LDS writes (disjoint buffers)
  }
}

// ---------- m201-style 8-phase 256x256 GEMM (R8-proven): C = A*BT^T ----------
// 8 phases / 2 K-tiles; reads 12/4/8/0 per phase; vmcnt(4) at ph4/ph8 only.
// EPI bits: 1=+bias, 2=gelu, 8=store bf16 (else f32)
template <int EPI>
__global__ __launch_bounds__(512, 2) void gemm8p(
    const bf16_t* __restrict__ A, int lda, const bf16_t* __restrict__ BT, int ldb,
    const float* __restrict__ bias, float* __restrict__ Cf, bf16_t* __restrict__ Cb,
    int M, int N, int K, size_t splitStride) {
  extern __shared__ __align__(16) char lds[];   // 128 KiB
  const int tid = threadIdx.x, wid = tid >> 6, lane = tid & 63;
  const int lc = lane & 15, lg = lane >> 4;
  const int bm = blockIdx.y * 256, bn = blockIdx.x * 256;
  const int wr = wid >> 2, wc = wid & 3;              // 2M x 4N waves, each 128x64 out
  const int NT = K >> 6, niter = NT >> 1;             // NT even
  const int srow = tid >> 3;
  const int scol = (((tid & 7) ^ ((tid >> 3) & 7)) << 3);
  const bf16_t* Abase = A + (size_t)blockIdx.z * K + (size_t)(bm + srow) * lda + scol;
  const bf16_t* Bbase = BT + (size_t)blockIdx.z * K + (size_t)(bn + srow) * ldb + scol;
  auto SA = [&](int T, int h) {
    char* dst = lds + (T & 1) * 32768 + h * 16384 + wid * 1024;
    const bf16_t* src = Abase + (size_t)(h * 128) * lda + T * 64;
    gload_lds16(src, dst); gload_lds16(src + (size_t)64 * lda, dst + 8192);
  };
  auto SB = [&](int T, int h) {
    char* dst = lds + 65536 + (T & 1) * 32768 + h * 16384 + wid * 1024;
    const bf16_t* src = Bbase + (size_t)(h * 128) * ldb + T * 64;
    gload_lds16(src, dst); gload_lds16(src + (size_t)64 * ldb, dst + 8192);
  };
#define FRA(d, row, kk) (*(const bfrag*)(lds + (d) * 32768 + wr * 16384 + (row) * 128 + \
    ((((kk) * 4 + lg) ^ ((row) & 7)) << 4)))
#define FRB(d, row, kk) (*(const bfrag*)(lds + 65536 + (d) * 32768 + (wc >> 1) * 16384 + \
    (row) * 128 + ((((kk) * 4 + lg) ^ ((row) & 7)) << 4)))
#define PHASE_SYNC() do { __builtin_amdgcn_s_barrier(); \
    asm volatile("s_waitcnt lgkmcnt(0)" ::: "memory"); \
    __builtin_amdgcn_sched_barrier(0); __builtin_amdgcn_s_setprio(1); } while (0)
#define PHASE_END() do { __builtin_amdgcn_s_setprio(0); __builtin_amdgcn_s_barrier(); } while (0)
#define PHASE_END_VM(lastf) do { __builtin_amdgcn_s_setprio(0); \
    if (lastf) asm volatile("s_waitcnt vmcnt(0)" ::: "memory"); \
    else       asm volatile("s_waitcnt vmcnt(4)" ::: "memory"); \
    __builtin_amdgcn_s_barrier(); } while (0)

  // prologue: tile0 all 4 halves + tile1 B halves
  SB(0, 0); SB(0, 1); SA(0, 0); SA(0, 1); SB(1, 0); SB(1, 1);
  asm volatile("s_waitcnt vmcnt(4)" ::: "memory");    // tile0 landed
  __builtin_amdgcn_s_barrier();

  f32x4 acc[8][4] = {};
  const int brl = (wc & 1) * 64 + lc;                 // B local row base (+n*16)

  for (int k = 0; k < niter; ++k) {
    const int T1 = 2 * k + 1, T2 = 2 * k + 2, T3 = 2 * k + 3;
    const bool last = (k == niter - 1);
    bfrag aq[4][2], b01[2][2], b23[2][2];
#pragma unroll 1
    for (int d = 0; d < 2; ++d) {                     // d=0: phases 1-4, d=1: phases 5-8
      // ---- phase 1/5: read a0-quad + b01; stage SA(T1,0) / SA(T2,0)
#pragma unroll
      for (int m = 0; m < 4; ++m)
#pragma unroll
        for (int kk = 0; kk < 2; ++kk) aq[m][kk] = FRA(d, m * 16 + lc, kk);
#pragma unroll
      for (int n = 0; n < 2; ++n)
#pragma unroll
        for (int kk = 0; kk < 2; ++kk) b01[n][kk] = FRB(d, brl + n * 16, kk);
      if (d == 0) SA(T1, 0); else if (!last) SA(T2, 0);
      PHASE_SYNC();
#pragma unroll
      for (int kk = 0; kk < 2; ++kk)
#pragma unroll
        for (int m = 0; m < 4; ++m) {
          acc[m][0] = MFMA16(aq[m][kk], b01[0][kk], acc[m][0]);
          acc[m][1] = MFMA16(aq[m][kk], b01[1][kk], acc[m][1]);
        }
      PHASE_END();
      // ---- phase 2/6: read b23; stage SA(T1,1) / SA(T2,1)
#pragma unroll
      for (int n = 0; n < 2; ++n)
#pragma unroll
        for (int kk = 0; kk < 2; ++kk) b23[n][kk] = FRB(d, brl + (n + 2) * 16, kk);
      if (d == 0) SA(T1, 1); else if (!last) SA(T2, 1);
      PHASE_SYNC();
#pragma unroll
      for (int kk = 0; kk < 2; ++kk)
#pragma unroll
        for (int m = 0; m < 4; ++m) {
          acc[m][2] = MFMA16(aq[m][kk], b23[0][kk], acc[m][2]);
          acc[m][3] = MFMA16(aq[m][kk], b23[1][kk], acc[m][3]);
        }
      PHASE_END();
      // ---- phase 3/7: read a1-quad; stage SB(T2,0) / SB(T3,0)
#pragma unroll
      for (int m = 0; m < 4; ++m)
#pragma unroll
        for (int kk = 0; kk < 2; ++kk) aq[m][kk] = FRA(d, (m + 4) * 16 + lc, kk);
      if (!last) { if (d == 0) SB(T2, 0); else SB(T3, 0); }
      PHASE_SYNC();
#pragma unroll
      for (int kk = 0; kk < 2; ++kk)
#pragma unroll
        for (int m = 0; m < 4; ++m) {
          acc[4 + m][2] = MFMA16(aq[m][kk], b23[0][kk], acc[4 + m][2]);
          acc[4 + m][3] = MFMA16(aq[m][kk], b23[1][kk], acc[4 + m][3]);
        }
      PHASE_END();
      // ---- phase 4/8: no reads; stage SB(T2,1) / SB(T3,1); counted vmcnt
      if (!last) { if (d == 0) SB(T2, 1); else SB(T3, 1); }
      PHASE_SYNC();
#pragma unroll
      for (int kk = 0; kk < 2; ++kk)
#pragma unroll
        for (int m = 0; m < 4; ++m) {
          acc[4 + m][0] = MFMA16(aq[m][kk], b01[0][kk], acc[4 + m][0]);
          acc[4 + m][1] = MFMA16(aq[m][kk], b01[1][kk], acc[4 + m][1]);
        }
      PHASE_END_VM(last);
    }
  }
#undef FRA
#undef FRB
#undef PHASE_SYNC
#undef PHASE_END
#undef PHASE_END_VM
  // ---- epilogue: per-wave LDS staging -> coalesced vector stores
  char* W = lds + wid * 16384;
  if (EPI & 8) {
    bf16_t* Wb = (bf16_t*)W;
    bf16_t* Cbz = Cb + (size_t)blockIdx.z * splitStride;
#pragma unroll
    for (int mc = 0; mc < 2; ++mc) {
#pragma unroll
      for (int m4 = 0; m4 < 4; ++m4) {
#pragma unroll
        for (int n = 0; n < 4; ++n) {
          const int col = bn + wc * 64 + n * 16 + lc;
          float bv = (EPI & 1) ? bias[col] : 0.f;
#pragma unroll
          for (int i = 0; i < 4; ++i) {
            float v = acc[mc * 4 + m4][n][i];
            if (EPI & 1) v += bv;
            if (EPI & 2) v = 0.5f * v * (1.f + tanhf(0.7978845608028654f * (v + 0.044715f * v * v * v)));
            Wb[(m4 * 16 + lg * 4 + i) * 72 + n * 16 + lc] = bf16_t(v);
          }
        }
      }
      asm volatile("s_waitcnt lgkmcnt(0)" ::: "memory");
      __builtin_amdgcn_sched_barrier(0);
#pragma unroll
      for (int p = 0; p < 8; ++p) {
        const int rl = p * 8 + (lane >> 3), j = lane & 7;
        uint4 v = *(const uint4*)&Wb[rl * 72 + j * 8];
        const int grow = bm + wr * 128 + mc * 64 + rl;
        const int gcol = bn + wc * 64 + j * 8;
        *(uint4*)&Cbz[(size_t)grow * N + gcol] = v;
      }
      asm volatile("s_waitcnt lgkmcnt(0)" ::: "memory");
      __builtin_amdgcn_sched_barrier(0);
    }
  } else {
    float* Wf = (float*)W;
    float* Cfz = Cf + (size_t)blockIdx.z * splitStride;
#pragma unroll
    for (int mc = 0; mc < 4; ++mc) {
#pragma unroll
      for (int m2 = 0; m2 < 2; ++m2) {
#pragma unroll
        for (int n = 0; n < 4; ++n) {
          const int col = bn + wc * 64 + n * 16 + lc;
          float bv = (EPI & 1) ? bias[col] : 0.f;
#pragma unroll
          for (int i = 0; i < 4; ++i) {
            float v = acc[mc * 2 + m2][n][i];
            if (EPI & 1) v += bv;
            if (EPI & 2) v = 0.5f * v * (1.f + tanhf(0.7978845608028654f * (v + 0.044715f * v * v * v)));
            Wf[(m2 * 16 + lg * 4 + i) * 72 + n * 16 + lc] = v;
          }
        }
      }
      asm volatile("s_waitcnt lgkmcnt(0)" ::: "memory");
      __builtin_amdgcn_sched_barrier(0);
#pragma unroll
      for (int p = 0; p < 8; ++p) {
        const int rl = p * 4 + (lane >> 4), j = lane & 15;
        float4 v = *(const float4*)&Wf[rl * 72 + j * 4];
        const int grow = bm + wr * 128 + mc * 32 + rl;
        const int gcol = bn + wc * 64 + j * 4;
        *(float4*)&Cfz[(size_t)grow * N + gcol] = v;
      }
      asm volatile("s_waitcnt lgkmcnt(0)" ::: "memory");
      __builtin_amdgcn_sched_barrier(0);
    }
  }
}

// ---------- final reduce: out = sum4(pa bf16) + sum4(pfb bf16) + b_ff_out[col] ----------
__global__ __launch_bounds__(256) void reduce_final(const bf16_t* __restrict__ pa,
    const bf16_t* __restrict__ pfb, const float* __restrict__ bias,
    float* __restrict__ out, int total) {
  const int i = (blockIdx.x * 256 + threadIdx.x) * 8;
  if (i >= total) return;
  const size_t S = 4194304;
  float r[8] = {};
#pragma unroll
  for (int z = 0; z < 4; ++z) {
    uint4 a = *(const uint4*)(pa + z * S + i);
    uint4 b = *(const uint4*)(pfb + z * S + i);
    const unsigned* ua = (const unsigned*)&a;
    const unsigned* ub = (const unsigned*)&b;
#pragma unroll
    for (int j = 0; j < 8; ++j) {
      const int w = j >> 1, sh = (j & 1) * 16;
      r[j] += bf2f((ua[w] >> sh) & 0xffffu) + bf2f((ub[w] >> sh) & 0xffffu);
    }
  }
  const int cb = i & 2047;
  float4 b0 = *(const float4*)(bias + cb);
  float4 b1 = *(const float4*)(bias + cb + 4);
  r[0] += b0.x; r[1] += b0.y; r[2] += b0.z; r[3] += b0.w;
  r[4] += b1.x; r[5] += b1.y; r[6] += b1.z; r[7] += b1.w;
  *(float4*)(out + i) = make_float4(r[0], r[1], r[2], r[3]);
  *(float4*)(out + i + 4) = make_float4(r[4], r[5], r[6], r[7]);
}

// ---------- RoPE + head split ----------
__global__ __launch_bounds__(128) void rope_kernel(const bf16_t* __restrict__ qkv,
    bf16_t* __restrict__ qh, bf16_t* __restrict__ kh, bf16_t* __restrict__ vT) {
  const int n = blockIdx.x, hh = blockIdx.y;
  const int d = threadIdx.x;
  const int mp = hh >> 2, hi = hh & 3;
  const bf16_t* row = qkv + (size_t)n * 6144 + mp * 1536 + hi * 128;  // [q|v|k] each 512 per mp
  float q = __bfloat162float(row[d]);
  float k = __bfloat162float(row[1024 + d]);
  if (d < 64) {  // wave-uniform branch
    const float ang = (float)n * powf(10000.f, -(float)(d & ~1) / 64.f);
    const float sn = sinf(ang), cs = cosf(ang);
    const float qp = __shfl_xor(q, 1), kp = __shfl_xor(k, 1);
    if (d & 1) { q = q * cs + qp * sn; k = k * cs + kp * sn; }
    else       { q = q * cs - qp * sn; k = k * cs - kp * sn; }
  }
  qh[((size_t)hh * 2048 + n) * 128 + d] = bf16_t(q * 0.08838834764831845f); // 1/sqrt(128)
  kh[((size_t)hh * 2048 + n) * 128 + d] = bf16_t(k);
  vT[((size_t)hh * 128 + d) * 2048 + n] = row[512 + d];
}

// ---------- causal flash attention, pairs + KV-split(z=3), partial (O,m,l) output ----------
__global__ __launch_bounds__(256) void attn_kernel(const bf16_t* __restrict__ qh,
    const bf16_t* __restrict__ kh, const bf16_t* __restrict__ vT,
    bf16_t* __restrict__ Op, float2* __restrict__ ml) {
  __shared__ alignas(16) char Kbuf[2][16384];    // [kv 64][d 128] bf16, chunk ^= row&15
  __shared__ alignas(16) char Vbuf[2][16384];    // [d 128][kv 64] bf16, chunk ^= row&7
  __shared__ alignas(16) bf16_t Ps[4][16 * 72];  // per-wave P, stride 72
  const int p = blockIdx.x, h = blockIdx.y, z = blockIdx.z;
  const int tid = threadIdx.x, wid = tid >> 6, lane = tid & 63;
  const int lc = lane & 15, lg = lane >> 4;
  const int krow = wid * 4 + (lane >> 4);
  const int vrow = wid * 8 + (lane >> 3);

  auto stage = [&](int kv0, int d) {
#pragma unroll
    for (int i = 0; i < 4; ++i) {
      const int kr = i * 16 + krow;
      const int kch = (lane & 15) ^ (kr & 15);
      gload_lds16(kh + ((size_t)h * 2048 + kv0 + kr) * 128 + kch * 8,
                  Kbuf[d] + i * 4096 + wid * 1024);
      const int vr = i * 32 + vrow;
      const int vch = (lane & 7) ^ (vr & 7);
      gload_lds16(vT + ((size_t)h * 128 + vr) * 2048 + kv0 + vch * 8,
                  Vbuf[d] + i * 4096 + wid * 1024);
    }
  };
#define FRK(d, row, ch) (*(const bfrag*)(Kbuf[d] + (row) * 256 + (((ch) ^ ((row) & 15)) << 4)))
#define FRV(d, row, ch) (*(const bfrag*)(Vbuf[d] + (row) * 128 + (((ch) ^ ((row) & 7)) << 4)))

#pragma unroll 1
  for (int half = 0; half < 2; ++half) {
    const int qt = half ? (31 - p) : p;
    const int nkv = qt + 1;
    const int lo = (z * nkv) / 3, hi = ((z + 1) * nkv) / 3;
    const int nj = hi - lo;
    const int qr = qt * 64 + wid * 16;
    const bf16_t* Qb = qh + ((size_t)h * 2048 + qr) * 128;
    bfrag qf[4];
#pragma unroll
    for (int ks = 0; ks < 4; ++ks)
      qf[ks] = *(const bfrag*)&Qb[lc * 128 + ks * 32 + lg * 8];
    f32x4 O[8] = {};
    float mr[4] = {-1e30f, -1e30f, -1e30f, -1e30f};
    float lsum[4] = {0.f, 0.f, 0.f, 0.f};

    if (nj > 0) {
      stage(lo * 64, 0);
      asm volatile("s_waitcnt vmcnt(0)" ::: "memory");
      __builtin_amdgcn_s_barrier();
    }
#pragma unroll 1
    for (int j = 0; j < nj; ++j) {
      const int kt = lo + j, d = j & 1;
      const int kv0 = kt * 64;
      if (j + 1 < nj) stage(kv0 + 64, d ^ 1);  // overlap with compute
      f32x4 s[4];
#pragma unroll
      for (int c = 0; c < 4; ++c) {
        f32x4 a = {};
#pragma unroll
        for (int ks = 0; ks < 4; ++ks) {
          bfrag kf = FRK(d, c * 16 + lc, ks * 4 + lg);
          a = MFMA16(qf[ks], kf, a);
        }
        s[c] = a;
      }
      if (kt == qt) {  // diagonal tile: causal mask
#pragma unroll
        for (int c = 0; c < 4; ++c)
#pragma unroll
          for (int i = 0; i < 4; ++i)
            if (kv0 + c * 16 + lc > qr + lg * 4 + i) s[c][i] = -1e10f;
      }
      float pm[4];
#pragma unroll
      for (int i = 0; i < 4; ++i)
        pm[i] = fmaxf(fmaxf(s[0][i], s[1][i]), fmaxf(s[2][i], s[3][i]));
#pragma unroll
      for (int m = 1; m < 16; m <<= 1)
#pragma unroll
        for (int i = 0; i < 4; ++i) pm[i] = fmaxf(pm[i], __shfl_xor(pm[i], m));
      // T13 defer-max: skip O-rescale when max growth <= 8 for all rows (wave-uniform)
      bool small = true;
#pragma unroll
      for (int i = 0; i < 4; ++i) small = small && (pm[i] <= mr[i] + 8.f);
      const bool skip = __all(small);
      float al[4], rs[4];
#pragma unroll
      for (int i = 0; i < 4; ++i) {
        const float mn = skip ? mr[i] : fmaxf(mr[i], pm[i]);
        al[i] = __expf(mr[i] - mn);
        mr[i] = mn;
        rs[i] = 0.f;
      }
#pragma unroll
      for (int c = 0; c < 4; ++c)
#pragma unroll
        for (int i = 0; i < 4; ++i) {
          const float pv = __expf(s[c][i] - mr[i]);
          s[c][i] = pv; rs[i] += pv;
        }
#pragma unroll
      for (int m = 1; m < 16; m <<= 1)
#pragma unroll
        for (int i = 0; i < 4; ++i) rs[i] += __shfl_xor(rs[i], m);
#pragma unroll
      for (int i = 0; i < 4; ++i) lsum[i] = lsum[i] * al[i] + rs[i];
      if (!skip) {
#pragma unroll
        for (int n = 0; n < 8; ++n)
#pragma unroll
          for (int i = 0; i < 4; ++i) O[n][i] *= al[i];
      }
#pragma unroll
      for (int c = 0; c < 4; ++c)
#pragma unroll
        for (int i = 0; i < 4; ++i)
          Ps[wid][(lg * 4 + i) * 72 + c * 16 + lc] = bf16_t(s[c][i]);
#pragma unroll
      for (int k2 = 0; k2 < 2; ++k2) {
        bfrag pf = *(const bfrag*)((const char*)&Ps[wid][0] + lc * 144 + k2 * 64 + lg * 16);
#pragma unroll
        for (int n = 0; n < 8; ++n) {
          bfrag vf = FRV(d, n * 16 + lc, k2 * 4 + lg);
          O[n] = MFMA16(pf, vf, O[n]);
        }
      }
      if (j + 1 < nj) asm volatile("s_waitcnt vmcnt(0)" ::: "memory");
      asm volatile("s_waitcnt lgkmcnt(0)" ::: "memory");
      __builtin_amdgcn_s_barrier();
    }
    const size_t rb = (size_t)(z * 16 + h) * 2048 + qr;
#pragma unroll
    for (int n = 0; n < 8; ++n)
#pragma unroll
      for (int i = 0; i < 4; ++i)
        Op[(rb + lg * 4 + i) * 128 + n * 16 + lc] = bf16_t(O[n][i]);
    if (lc == 0) {
#pragma unroll
      for (int i = 0; i < 4; ++i)
        ml[rb + lg * 4 + i] = make_float2(mr[i], lsum[i]);
    }
    __builtin_amdgcn_s_barrier();
  }
#undef FRK
#undef FRV
}

// ---------- combine z=3 attention partials -> av bf16 [2048][2048] ----------
__global__ __launch_bounds__(256) void attn_combine(const bf16_t* __restrict__ Op,
    const float2* __restrict__ ml, bf16_t* __restrict__ av) {
  const int idx = blockIdx.x * 256 + threadIdx.x;
  const int t = idx & 15, hr = idx >> 4;
  const int ZS = 16 * 2048;
  const size_t ZO = (size_t)ZS * 128;
  const float2 m0 = ml[hr], m1 = ml[ZS + hr], m2 = ml[2 * ZS + hr];
  const float M = fmaxf(fmaxf(m0.x, m1.x), m2.x);
  const float w0 = __expf(m0.x - M), w1 = __expf(m1.x - M), w2 = __expf(m2.x - M);
  const float inv = 1.f / (w0 * m0.y + w1 * m1.y + w2 * m2.y);
  const bf16_t* p0 = Op + (size_t)hr * 128 + t * 8;
  uint4 a0 = *(const uint4*)p0;
  uint4 a1 = *(const uint4*)(p0 + ZO);
  uint4 a2 = *(const uint4*)(p0 + 2 * ZO);
  const unsigned* u0 = (const unsigned*)&a0;
  const unsigned* u1 = (const unsigned*)&a1;
  const unsigned* u2 = (const unsigned*)&a2;
  bf16_t ov[8];
#pragma unroll
  for (int j = 0; j < 8; ++j) {
    const int w = j >> 1, sh = (j & 1) * 16;
    ov[j] = bf16_t((w0 * bf2f((u0[w] >> sh) & 0xffffu) +
                    w1 * bf2f((u1[w] >> sh) & 0xffffu) +
                    w2 * bf2f((u2[w] >> sh) & 0xffffu)) * inv);
  }
  const int row = hr & 2047, hh = hr >> 11;
  *(uint4*)(av + (size_t)row * 2048 + hh * 128 + t * 8) = *(const uint4*)ov;
}

extern "C" void kernel_launch(void* const* d_in, const int* in_sizes, int n_in,
                              void* d_out, int out_size, void* d_ws, size_t ws_size,
                              hipStream_t stream) {
  const float* x        = (const float*)d_in[0];
  const float* ln_scale = (const float*)d_in[1];
  const float* ln_offset= (const float*)d_in[2];
  const float* w_qkv    = (const float*)d_in[3];   // [2048][6144]
  const float* w_ao     = (const float*)d_in[4];   // [2048][2048]
  const float* w_ff_in  = (const float*)d_in[5];   // [2048][8192]
  const float* b_ff_in  = (const float*)d_in[6];   // [8192]
  const float* w_ff_out = (const float*)d_in[7];   // [8192][2048]
  const float* b_ff_out = (const float*)d_in[8];   // [2048]
  float* out = (float*)d_out;

  char* ws = (char*)d_ws;
  // live ranges (proven footprint <= 176.2 MB):
  bf16_t* wqkvT   = (bf16_t*)(ws);                  // 0-25.2    dead after qkv gemm
  bf16_t* waoT    = (bf16_t*)(ws + 25165824);       // 25.2-33.6 dead after attn_out gemm
  bf16_t* wffinT  = (bf16_t*)(ws + 33554432);       // 33.6-67.2 dead after ff_in gemm
  bf16_t* wffoutT = (bf16_t*)(ws + 67108864);       // 67.2-100.7 dead after ff_out gemm
  bf16_t* h       = (bf16_t*)(ws + 100663296);      // 100.7-109.1 dead after ff_in gemm
  bf16_t* qhb     = (bf16_t*)(ws + 109051904);      // [16][2048][128]
  bf16_t* khb     = (bf16_t*)(ws + 117440512);
  bf16_t* vTb     = (bf16_t*)(ws + 125829120);      // [16][128][2048]
  bf16_t* avb     = (bf16_t*)(ws + 134217728);      // [2048][2048]
  bf16_t* qkvb    = (bf16_t*)(ws + 142606336);      // 142.6-167.8 dead after rope
  bf16_t* ff1b    = qkvb;                           // ff1 [2048][8192] 142.6-176.2 (after rope)
  bf16_t* Opart   = (bf16_t*)(ws);                  // attn partials 3x8.4MB over dead wqkvT
  float2* mlpart  = (float2*)(ws + 100663296);      // 786KB over dead h (after ff_in)
  bf16_t* pab     = (bf16_t*)(ws + 33554432);       // attn_out partials 4x8.4MB over dead wffinT
  bf16_t* pfb     = (bf16_t*)(ws);                  // ff_out partials 4x8.4MB over dead wqkvT/waoT

  hipFuncSetAttribute((const void*)gemm8p<8>,  hipFuncAttributeMaxDynamicSharedMemorySize, 131072);
  hipFuncSetAttribute((const void*)gemm8p<11>, hipFuncAttributeMaxDynamicSharedMemorySize, 131072);

  dim3 b256(256), b512(512);
  // weights transpose (2 tiles/block, dbuf) + LN, one launch
  prep_kernel<<<dim3(8192), b256, 0, stream>>>(w_qkv, wqkvT, w_ao, waoT,
      w_ff_in, wffinT, w_ff_out, wffoutT, x, ln_scale, ln_offset, h);

  gemm8p<8><<<dim3(24, 8, 1), b512, 131072, stream>>>(h, 2048, wqkvT, 2048,
      nullptr, nullptr, qkvb, 2048, 6144, 2048, 0);
  rope_kernel<<<dim3(2048, 16), dim3(128), 0, stream>>>(qkvb, qhb, khb, vTb);

  // ff_in early (frees wffinT + h for later partials); writes ff1b over dead qkvb
  gemm8p<11><<<dim3(32, 8, 1), b512, 131072, stream>>>(h, 2048, wffinT, 2048,
      b_ff_in, nullptr, ff1b, 2048, 8192, 2048, 0);

  attn_kernel<<<dim3(16, 16, 3), b256, 0, stream>>>(qhb, khb, vTb, Opart, mlpart);
  attn_combine<<<dim3(2048), b256, 0, stream>>>(Opart, mlpart, avb);

  // attn_out: split-K=4 (K=512), bf16 partials over dead wffinT
  gemm8p<8><<<dim3(8, 8, 4), b512, 131072, stream>>>(avb, 2048, waoT, 2048,
      nullptr, nullptr, pab, 2048, 2048, 512, (size_t)2048 * 2048);

  // ff_out: split-K=4 (K=2048), bf16 partials over dead wqkvT/waoT
  gemm8p<8><<<dim3(8, 8, 4), b512, 131072, stream>>>(ff1b, 8192, wffoutT, 8192,
      nullptr, nullptr, pfb, 2048, 2048, 2048, (size_t)2048 * 2048);

  // single fused reduce: out = sum(pab) + sum(pfb) + b_ff_out
  reduce_final<<<dim3(2048), b256, 0, stream>>>(pab, pfb, b_ff_out, out, 4194304);
}